// Round 13
// baseline (219.554 us; speedup 1.0000x reference)
//
#include <hip/hip_runtime.h>
#include <cstdint>
#include <cstddef>

#define L_SEQ   2048
#define DMODEL  1024
#define DINNER  2048
#define NHEADS_ 32
#define HEADDIM_ 64
#define DSTATE  64
#define CONVDIM 2304
#define DINPROJ 4416
#define DINPROJ_P 4608   // padded to 256-multiple for the 8-phase tile
#define BATCH_  2
#define EPS_    1e-5f
#define PITCH   72       // LDS tile pitch in bf16 elems (144B rows)
#define KSPL    8        // diag GEMM K-split

typedef __attribute__((ext_vector_type(8))) short bf16x8;
typedef __attribute__((ext_vector_type(4))) float f32x4;
typedef unsigned short ushort_t;
typedef unsigned int uint_t;
typedef __attribute__((address_space(3))) unsigned int as3_uint;
typedef __attribute__((address_space(1))) const unsigned int as1_uint;

__device__ __forceinline__ float silu_f(float v) { return v / (1.f + __expf(-v)); }
__device__ __forceinline__ ushort_t f2bf(float f) {
    uint_t u = __float_as_uint(f);
    return (ushort_t)((u + 0x7FFFu + ((u >> 16) & 1u)) >> 16);   // RNE
}
__device__ __forceinline__ float bf2f(ushort_t u) {
    return __uint_as_float(((uint_t)u) << 16);
}
__device__ __forceinline__ void gload16(const void* g, void* l) {
    __builtin_amdgcn_global_load_lds((as1_uint*)g, (as3_uint*)l, 16, 0, 0);
}

// ---------------- merged fp32 -> bf16 conversions (4 segments, 1 launch) --------------
#define N0U ((size_t)(4096 * 1024 / 4))          // u
#define N1U ((size_t)(DINPROJ_P * DMODEL / 4))   // W_in zero-padded to 4608 rows
#define N2U ((size_t)(DMODEL * DINNER / 4))      // W_out
#define N3U ((size_t)(64 * DINNER / 4))          // fc_D zero-padded
__global__ __launch_bounds__(256)
void cvt_all(const float* __restrict__ u, const float* __restrict__ W_in,
             const float* __restrict__ W_out, const float* __restrict__ fcD,
             ushort_t* __restrict__ ubf, ushort_t* __restrict__ wibf,
             ushort_t* __restrict__ wobf, ushort_t* __restrict__ fcdbf) {
    size_t unit = (size_t)blockIdx.x * 256 + threadIdx.x;
    if (unit >= N0U + N1U + N2U + N3U) return;
    const float* src; ushort_t* dst; size_t i4; bool zero = false;
    if (unit < N0U) {
        i4 = unit; src = u; dst = ubf;
    } else if (unit < N0U + N1U) {
        i4 = unit - N0U; src = W_in; dst = wibf;
        zero = ((int)(i4 / (DMODEL / 4)) >= DINPROJ);
    } else if (unit < N0U + N1U + N2U) {
        i4 = unit - N0U - N1U; src = W_out; dst = wobf;
    } else {
        i4 = unit - N0U - N1U - N2U; src = fcD; dst = fcdbf;
        zero = ((int)(i4 / (DINNER / 4)) >= NHEADS_);
    }
    float4 v = zero ? make_float4(0.f, 0.f, 0.f, 0.f)
                    : reinterpret_cast<const float4*>(src)[i4];
    ushort_t* d = dst + i4 * 4;
    d[0] = f2bf(v.x); d[1] = f2bf(v.y); d[2] = f2bf(v.z); d[3] = f2bf(v.w);
}

// ---------------- 8-phase 256x256 bf16 MFMA GEMM (gemm1): Cbf = A * B^T ---------------
// 512 threads = 8 waves (2 x 4). BK=64, double-buffered 128KB LDS, counted vmcnt,
// per-phase barriers + lgkmcnt(0)+sched_barrier + setprio around MFMA clusters.
// LDS rows 128B, 3-bit XOR slot swizzle (source-preswizzled for global_load_lds).
__global__ __launch_bounds__(512, 2)
void gemm_8ph(const ushort_t* __restrict__ Ap, const ushort_t* __restrict__ Bp,
              ushort_t* __restrict__ Cbf, int M, int N, int K, int nbn) {
    const int nwg = gridDim.x;
    const int orig = blockIdx.x;
    const int xcd = orig & 7, q_ = nwg >> 3, r_ = nwg & 7;
    const int wg = ((xcd < r_) ? (xcd * (q_ + 1)) : (r_ * (q_ + 1) + (xcd - r_) * q_)) + (orig >> 3);
    const int bm = (wg / nbn) * 256, bn = (wg % nbn) * 256;

    __shared__ __align__(16) char smem[131072];   // 2 bufs x (A 32KB | B 32KB); epilogue reuses all

    const int tid = threadIdx.x;
    const int wave = tid >> 6, lane = tid & 63;
    const int wr = wave >> 2, wc = wave & 3;      // 2 x 4 wave grid
    const int fr = lane & 15, kg = lane >> 4, rg = lane >> 4;

    // ---- staging setup: 8 gloads/wave/K-tile; unit i>>1 in {A0,B0,A1,B1}, g=i&1 ----
    const ushort_t* gptr[8]; uint_t glds[8];
#pragma unroll
    for (int i = 0; i < 8; ++i) {
        int unit = i >> 1, g = i & 1;
        int isB = unit & 1, half = unit >> 1;
        int rbase = half * 128 + wave * 16 + g * 8;
        int rl = rbase + (lane >> 3);
        int slot = (lane & 7) ^ (lane >> 3);      // rl&7 == lane>>3 (rbase 8-aligned)
        gptr[i] = (isB ? Bp : Ap) + (size_t)((isB ? bn : bm) + rl) * (size_t)K + slot * 8;
        glds[i] = (uint_t)(isB * 32768 + rbase * 128);
    }
    auto stage = [&](int pbuf, int t) {
#pragma unroll
        for (int i = 0; i < 8; ++i)
            gload16(gptr[i] + (size_t)t * 64, smem + pbuf * 65536 + glds[i]);
    };

    f32x4 acc[8][4];
#pragma unroll
    for (int m = 0; m < 8; ++m)
#pragma unroll
        for (int n = 0; n < 4; ++n) acc[m][n] = (f32x4){0.f, 0.f, 0.f, 0.f};

    bf16x8 aF[4][2];        // current mh-half A frags
    bf16x8 bF[2][2][2];     // both nh B frag sets persist

    auto lda_frag = [&](int pbuf, int mh) {
#pragma unroll
        for (int mm = 0; mm < 4; ++mm)
#pragma unroll
            for (int kk = 0; kk < 2; ++kk) {
                int Rl = wr * 128 + mh * 64 + mm * 16 + fr;
                aF[mm][kk] = *reinterpret_cast<const bf16x8*>(
                    smem + pbuf * 65536 + Rl * 128 + (((kk * 4 + kg) ^ (Rl & 7)) << 4));
            }
    };
    auto ldb_frag = [&](int pbuf, int nh) {
#pragma unroll
        for (int nn = 0; nn < 2; ++nn)
#pragma unroll
            for (int kk = 0; kk < 2; ++kk) {
                int Rl = wc * 64 + (nh * 2 + nn) * 16 + fr;
                bF[nh][nn][kk] = *reinterpret_cast<const bf16x8*>(
                    smem + pbuf * 65536 + 32768 + Rl * 128 + (((kk * 4 + kg) ^ (Rl & 7)) << 4));
            }
    };
    auto do_mfma = [&](int mh, int nh) {
        __builtin_amdgcn_s_setprio(1);
#pragma unroll
        for (int mm = 0; mm < 4; ++mm)
#pragma unroll
            for (int nn = 0; nn < 2; ++nn)
#pragma unroll
                for (int kk = 0; kk < 2; ++kk)
                    acc[mh * 4 + mm][nh * 2 + nn] = __builtin_amdgcn_mfma_f32_16x16x32_bf16(
                        aF[mm][kk], bF[nh][nn][kk], acc[mh * 4 + mm][nh * 2 + nn], 0, 0, 0);
        __builtin_amdgcn_s_setprio(0);
    };

    const int NT = K / 64;
    // prologue: tile 0
    stage(0, 0);
    asm volatile("s_waitcnt vmcnt(0)" ::: "memory");
    __builtin_amdgcn_sched_barrier(0);
    __builtin_amdgcn_s_barrier();

    for (int t = 0; t < NT; ++t) {
        const int p = t & 1;
        // ---- phase 0: prefetch issue + counted wait + quadrant (0,0) ----
        if (t + 1 < NT) stage(p ^ 1, t + 1);
        if (t > 0) {
            if (t + 1 < NT) asm volatile("s_waitcnt vmcnt(8)" ::: "memory");
            else            asm volatile("s_waitcnt vmcnt(0)" ::: "memory");
            __builtin_amdgcn_sched_barrier(0);
        }
        __builtin_amdgcn_s_barrier();          // all waves' DMA for tile t landed
        lda_frag(p, 0); ldb_frag(p, 0);
        asm volatile("s_waitcnt lgkmcnt(0)" ::: "memory");
        __builtin_amdgcn_sched_barrier(0);
        do_mfma(0, 0);
        __builtin_amdgcn_s_barrier();
        // ---- phase 1: quadrant (0,1) ----
        ldb_frag(p, 1);
        asm volatile("s_waitcnt lgkmcnt(0)" ::: "memory");
        __builtin_amdgcn_sched_barrier(0);
        do_mfma(0, 1);
        __builtin_amdgcn_s_barrier();
        // ---- phase 2: quadrant (1,0) ----
        lda_frag(p, 1);
        asm volatile("s_waitcnt lgkmcnt(0)" ::: "memory");
        __builtin_amdgcn_sched_barrier(0);
        do_mfma(1, 0);
        __builtin_amdgcn_s_barrier();
        // ---- phase 3: quadrant (1,1) ----
        do_mfma(1, 1);
        __builtin_amdgcn_s_barrier();
    }

    // ---- epilogue: LDS-staged coalesced bf16 C-write (256x256 = 128KB) ----
    char* ct = smem;
#pragma unroll
    for (int m = 0; m < 8; ++m)
#pragma unroll
        for (int n = 0; n < 4; ++n) {
#pragma unroll
            for (int r = 0; r < 4; ++r) {
                int lr = wr * 128 + m * 16 + rg * 4 + r;
                int lc = wc * 64 + n * 16 + fr;
                int byte = lr * 512 + ((lc * 2) ^ ((lr & 7) << 4));
                *reinterpret_cast<ushort_t*>(ct + byte) = f2bf(acc[m][n][r]);
            }
        }
    __syncthreads();
    for (int pass = 0; pass < 16; ++pass) {
        int unit = pass * 512 + tid;               // 8192 units of 16B
        int row = unit >> 5, u = unit & 31;
        uint4 v = *reinterpret_cast<const uint4*>(ct + row * 512 + ((u * 16) ^ ((row & 7) << 4)));
        *reinterpret_cast<uint4*>(&Cbf[(size_t)(bm + row) * N + bn + u * 8]) = v;
    }
}

// ---------------- bf16 MFMA GEMM (128-tile template, gemm3 + diag) --------------------
// MODE 0: fp32 C, LDS epilogue. MODE 2: K-split partials.
template<int BM, int BN, int WGM, int WGN, int FM, int FN, int MODE>
__global__ __launch_bounds__(256)
void gemm_nt_mfma(const ushort_t* __restrict__ A, const ushort_t* __restrict__ B,
                  float* __restrict__ C, ushort_t* __restrict__ Cbf,
                  int M, int N, int K, int lda, int ldb, int nbn) {
    const int nwg = gridDim.x;
    const int orig = blockIdx.x;
    const int xcd = orig & 7, q = nwg >> 3, r = nwg & 7;
    const int wg = ((xcd < r) ? (xcd * (q + 1)) : (r * (q + 1) + (xcd - r) * q)) + (orig >> 3);

    int bm, bn, kbeg, kend, ks = 0;
    if (MODE == 2) {
        bm = (wg / nbn) * BM; bn = 0; ks = wg % nbn;
        kbeg = ks * (K / nbn); kend = kbeg + K / nbn;
    } else {
        bm = (wg / nbn) * BM; bn = (wg % nbn) * BN;
        kbeg = 0; kend = K;
    }

    constexpr int BUFSZ = (BM + BN) * 64;
    constexpr int EPI_B = (MODE == 2) ? 0 : BM * 256;
    constexpr int SMEM_B = (2 * BUFSZ > EPI_B) ? 2 * BUFSZ : EPI_B;
    __shared__ __align__(16) char smem[SMEM_B];

    const int tid = threadIdx.x;
    const int wave = tid >> 6, lane = tid & 63;
    const int wr = wave / WGN, wc = wave % WGN;
    const int fr = lane & 15, kg = lane >> 4;

    constexpr int AI = BM / 64, BI = BN / 64;
    size_t aoff[AI]; int aLds[AI];
#pragma unroll
    for (int pp = 0; pp < AI; ++pp) {
        int p = wave * AI + pp;
        int row = p * 16 + (lane >> 2);
        int c16 = (lane & 3) ^ ((row >> 1) & 3);
        aoff[pp] = (size_t)(bm + row) * lda + c16 * 8;
        aLds[pp] = p * 1024;
    }
    size_t boff[BI]; int bLds[BI];
#pragma unroll
    for (int pp = 0; pp < BI; ++pp) {
        int p = wave * BI + pp;
        int row = p * 16 + (lane >> 2);
        int c16 = (lane & 3) ^ ((row >> 1) & 3);
        boff[pp] = (size_t)(bn + row) * ldb + c16 * 8;
        bLds[pp] = BM * 64 + p * 1024;
    }

    auto stage = [&](int buf, int k0) {
        char* bp = smem + buf * BUFSZ;
#pragma unroll
        for (int pp = 0; pp < AI; ++pp) gload16(&A[aoff[pp] + k0], bp + aLds[pp]);
#pragma unroll
        for (int pp = 0; pp < BI; ++pp) gload16(&B[boff[pp] + k0], bp + bLds[pp]);
    };

    f32x4 acc[FM][FN];
#pragma unroll
    for (int m = 0; m < FM; ++m)
#pragma unroll
        for (int n = 0; n < FN; ++n) acc[m][n] = (f32x4){0.f, 0.f, 0.f, 0.f};

    stage(0, kbeg);
    __syncthreads();

    const int NT = (kend - kbeg) / 32;
    for (int t = 0; t < NT; ++t) {
        const int cur = t & 1;
        if (t + 1 < NT) stage(cur ^ 1, kbeg + (t + 1) * 32);

        const char* bp = smem + cur * BUFSZ;
        bf16x8 af[FM], bfv[FN];
#pragma unroll
        for (int m = 0; m < FM; ++m) {
            int row = wr * FM * 16 + m * 16 + fr;
            af[m] = *reinterpret_cast<const bf16x8*>(bp + row * 64 + ((kg ^ ((row >> 1) & 3)) << 4));
        }
#pragma unroll
        for (int n = 0; n < FN; ++n) {
            int row = wc * FN * 16 + n * 16 + fr;
            bfv[n] = *reinterpret_cast<const bf16x8*>(bp + BM * 64 + row * 64 + ((kg ^ ((row >> 1) & 3)) << 4));
        }
#pragma unroll
        for (int m = 0; m < FM; ++m)
#pragma unroll
            for (int n = 0; n < FN; ++n)
                acc[m][n] = __builtin_amdgcn_mfma_f32_16x16x32_bf16(af[m], bfv[n], acc[m][n], 0, 0, 0);
        __syncthreads();
    }

    const int rg = lane >> 4;
    if (MODE == 2) {
        float* Cp = C + (size_t)ks * M * NHEADS_;
#pragma unroll
        for (int m = 0; m < FM; ++m)
#pragma unroll
            for (int n = 0; n < FN; ++n) {
                int col = wc * FN * 16 + n * 16 + fr;
#pragma unroll
                for (int r = 0; r < 4; ++r) {
                    int rowg = bm + wr * FM * 16 + m * 16 + rg * 4 + r;
                    if (col < NHEADS_) Cp[(size_t)rowg * NHEADS_ + col] = acc[m][n][r];
                }
            }
    } else {
        char* ct = smem;
#pragma unroll
        for (int m = 0; m < FM; ++m)
#pragma unroll
            for (int n = 0; n < FN; ++n) {
#pragma unroll
                for (int r = 0; r < 4; ++r) {
                    int lr = wr * FM * 16 + m * 16 + rg * 4 + r;
                    int lc = wc * FN * 16 + n * 16 + fr;
                    int byte = (lr * 256 + lc * 4) ^ ((lr & 7) << 4);
                    *reinterpret_cast<float*>(ct + byte) = acc[m][n][r];
                }
            }
        __syncthreads();
        const int lrow = tid >> 4, seg16 = (tid & 15) * 16;
#pragma unroll
        for (int j = 0; j < BM / 16; ++j) {
            int lr = j * 16 + lrow;
            uint4 v = *reinterpret_cast<const uint4*>(ct + ((lr * 256 + seg16) ^ ((lr & 7) << 4)));
            *reinterpret_cast<uint4*>(&C[(size_t)(bm + lr) * N + bn + seg16 / 4]) = v;
        }
    }
}

// ---------------- depthwise conv + bias + SiLU -> bf16 xBC ----------------------------
__global__ __launch_bounds__(256)
void conv_kernel(const ushort_t* __restrict__ zxbf, const float* __restrict__ conv_w,
                 const float* __restrict__ conv_b, ushort_t* __restrict__ xBCbf) {
    const int c = blockIdx.x * 256 + threadIdx.x;   // channel 0..2303
    const int t0 = blockIdx.y * 16;
    const int beta = blockIdx.z;
    float w[7];
#pragma unroll
    for (int k = 0; k < 7; ++k) w[k] = conv_w[c * 7 + k];
    const float bias = conv_b[c];
    const ushort_t* in = zxbf + (size_t)beta * L_SEQ * DINPROJ_P + DINNER + c;
    float win[7];
#pragma unroll
    for (int j = 0; j < 6; ++j) {
        int t = t0 - 3 + j;
        win[j] = (t >= 0 && t < L_SEQ) ? bf2f(in[(size_t)t * DINPROJ_P]) : 0.f;
    }
    for (int i = 0; i < 16; ++i) {
        int t = t0 + i;
        int tl = t + 3;
        win[6] = (tl < L_SEQ) ? bf2f(in[(size_t)tl * DINPROJ_P]) : 0.f;
        float acc = bias;
#pragma unroll
        for (int k = 0; k < 7; ++k) acc += win[k] * w[k];
        xBCbf[((size_t)beta * L_SEQ + t) * CONVDIM + c] = f2bf(silu_f(acc));
#pragma unroll
        for (int j = 0; j < 6; ++j) win[j] = win[j + 1];
    }
}

// ---------------- log-decay precompute: la[bd][h][tau] = A_h * softplus(dt+bias) ------
__global__ __launch_bounds__(256)
void dtla_kernel(const ushort_t* __restrict__ zxbf, const float* __restrict__ dt_bias,
                 const float* __restrict__ A_log, float* __restrict__ labuf) {
    const int idx = blockIdx.x * 256 + threadIdx.x;     // 4*2048*32
    const int h   = idx & 31;
    const int tau = (idx >> 5) & (L_SEQ - 1);
    const int bd  = idx >> 16;
    const int dir = bd >> 1, beta = bd & 1;
    const int tt  = dir ? (L_SEQ - 1 - tau) : tau;
    const float dtraw = bf2f(zxbf[((size_t)beta * L_SEQ + tt) * DINPROJ_P + DINNER + CONVDIM + dir * NHEADS_ + h]);
    const float Ah = -__expf(A_log[h]);
    const float dtv = dtraw + dt_bias[h];
    const float sp = (dtv > 15.f) ? dtv : log1pf(__expf(dtv));
    labuf[((size_t)bd * NHEADS_ + h) * L_SEQ + tau] = Ah * sp;
}

// ---------------- SSD chunk kernel (K_A): chunk-parallel intra work --------------------
__global__ __launch_bounds__(256)
void ssd_chunk_kernel(const ushort_t* __restrict__ xBCbf, const float* __restrict__ labuf,
                      float* __restrict__ Pbuf, ushort_t* __restrict__ sdel,
                      ushort_t* __restrict__ yfw, ushort_t* __restrict__ ybw) {
    const int c  = blockIdx.x;
    const int h  = blockIdx.y;
    const int bd = blockIdx.z;
    const int dir = bd >> 1, beta = bd & 1;
    const int tid = threadIdx.x;
    const int wave = tid >> 6, lane = tid & 63;
    const int wr = wave >> 1, wc = wave & 1;
    const int fr = lane & 15, kg = lane >> 4, rg = lane >> 4;

    __shared__ short Bs[64 * PITCH], Cs[64 * PITCH], XTs[64 * PITCH],
                     BTs[64 * PITCH], Ms[64 * PITCH];
    __shared__ float lslds[64];

    const int row = tid >> 2, seg = tid & 3;
    const int tau_r = c * 64 + row;
    const int tt = dir ? (L_SEQ - 1 - tau_r) : tau_r;
    const ushort_t* gbase = xBCbf + ((size_t)beta * L_SEQ + tt) * CONVDIM;

    union U4 { uint4 v; ushort_t s[8]; };
    U4 x0, x1, b0, b1, c0, c1;
    x0.v = *reinterpret_cast<const uint4*>(gbase + h * 64 + seg * 16);
    x1.v = *reinterpret_cast<const uint4*>(gbase + h * 64 + seg * 16 + 8);
    b0.v = *reinterpret_cast<const uint4*>(gbase + DINNER + dir * 128 + seg * 16);
    b1.v = *reinterpret_cast<const uint4*>(gbase + DINNER + dir * 128 + seg * 16 + 8);
    c0.v = *reinterpret_cast<const uint4*>(gbase + DINNER + dir * 128 + 64 + seg * 16);
    c1.v = *reinterpret_cast<const uint4*>(gbase + DINNER + dir * 128 + 64 + seg * 16 + 8);

    *reinterpret_cast<uint4*>(&Bs[row * PITCH + seg * 16])     = b0.v;
    *reinterpret_cast<uint4*>(&Bs[row * PITCH + seg * 16 + 8]) = b1.v;
    *reinterpret_cast<uint4*>(&Cs[row * PITCH + seg * 16])     = c0.v;
    *reinterpret_cast<uint4*>(&Cs[row * PITCH + seg * 16 + 8]) = c1.v;
#pragma unroll
    for (int k = 0; k < 8; ++k) {
        XTs[(seg * 16 + k) * PITCH + row]     = x0.s[k];
        XTs[(seg * 16 + 8 + k) * PITCH + row] = x1.s[k];
    }

    if (tid < 64) {
        float v = labuf[((size_t)bd * NHEADS_ + h) * L_SEQ + c * 64 + tid];
#pragma unroll
        for (int d = 1; d < 64; d <<= 1) {
            float t = __shfl_up(v, d);
            if (lane >= d) v += t;
        }
        lslds[tid] = v;
        Pbuf[((size_t)bd * NHEADS_ + h) * L_SEQ + c * 64 + tid] = __expf(v);
    }
    __syncthreads();

    {
        const float wrow = __expf(lslds[63] - lslds[row]);
#pragma unroll
        for (int k = 0; k < 8; ++k) {
            BTs[(seg * 16 + k) * PITCH + row]     = (short)f2bf(bf2f(b0.s[k]) * wrow);
            BTs[(seg * 16 + 8 + k) * PITCH + row] = (short)f2bf(bf2f(b1.s[k]) * wrow);
        }
    }

    // ---- G = C @ B^T ----
    f32x4 accg[2][2];
#pragma unroll
    for (int mi = 0; mi < 2; ++mi)
#pragma unroll
        for (int nj = 0; nj < 2; ++nj) accg[mi][nj] = (f32x4){0.f, 0.f, 0.f, 0.f};
#pragma unroll
    for (int s = 0; s < 2; ++s) {
        int koff = kg * 8 + s * 32;
        bf16x8 af[2], bfv[2];
#pragma unroll
        for (int mi = 0; mi < 2; ++mi)
            af[mi] = *reinterpret_cast<const bf16x8*>(&Cs[(wr * 32 + mi * 16 + fr) * PITCH + koff]);
#pragma unroll
        for (int nj = 0; nj < 2; ++nj)
            bfv[nj] = *reinterpret_cast<const bf16x8*>(&Bs[(wc * 32 + nj * 16 + fr) * PITCH + koff]);
#pragma unroll
        for (int mi = 0; mi < 2; ++mi)
#pragma unroll
            for (int nj = 0; nj < 2; ++nj)
                accg[mi][nj] = __builtin_amdgcn_mfma_f32_16x16x32_bf16(af[mi], bfv[nj], accg[mi][nj], 0, 0, 0);
    }

    // ---- M = mask .* exp(ls_i - ls_j) .* G -> bf16 LDS ----
#pragma unroll
    for (int mi = 0; mi < 2; ++mi)
#pragma unroll
        for (int nj = 0; nj < 2; ++nj) {
            int j = wc * 32 + nj * 16 + fr;
            float lsj = lslds[j];
#pragma unroll
            for (int r = 0; r < 4; ++r) {
                int i = wr * 32 + mi * 16 + rg * 4 + r;
                float v = accg[mi][nj][r];
                v = (i >= j) ? v * __expf(lslds[i] - lsj) : 0.f;
                Ms[i * PITCH + j] = (short)f2bf(v);
            }
        }
    __syncthreads();   // after this barrier Bs/Cs are no longer read -> reusable

    // ---- Y_intra = M @ X ; S_delta = X^T @ Bw ----
    f32x4 accy[2][2], accs[2][2];
#pragma unroll
    for (int mi = 0; mi < 2; ++mi)
#pragma unroll
        for (int nj = 0; nj < 2; ++nj) {
            accy[mi][nj] = (f32x4){0.f, 0.f, 0.f, 0.f};
            accs[mi][nj] = (f32x4){0.f, 0.f, 0.f, 0.f};
        }
#pragma unroll
    for (int s = 0; s < 2; ++s) {
        int koff = kg * 8 + s * 32;
        bf16x8 am[2], axt[2], bxt[2], bbt[2];
#pragma unroll
        for (int mi = 0; mi < 2; ++mi) {
            am[mi]  = *reinterpret_cast<const bf16x8*>(&Ms[(wr * 32 + mi * 16 + fr) * PITCH + koff]);
            axt[mi] = *reinterpret_cast<const bf16x8*>(&XTs[(wr * 32 + mi * 16 + fr) * PITCH + koff]);
        }
#pragma unroll
        for (int nj = 0; nj < 2; ++nj) {
            bxt[nj] = *reinterpret_cast<const bf16x8*>(&XTs[(wc * 32 + nj * 16 + fr) * PITCH + koff]);
            bbt[nj] = *reinterpret_cast<const bf16x8*>(&BTs[(wc * 32 + nj * 16 + fr) * PITCH + koff]);
        }
#pragma unroll
        for (int mi = 0; mi < 2; ++mi)
#pragma unroll
            for (int nj = 0; nj < 2; ++nj) {
                accy[mi][nj] = __builtin_amdgcn_mfma_f32_16x16x32_bf16(am[mi], bxt[nj], accy[mi][nj], 0, 0, 0);
                accs[mi][nj] = __builtin_amdgcn_mfma_f32_16x16x32_bf16(axt[mi], bbt[nj], accs[mi][nj], 0, 0, 0);
            }
    }

    // ---- stage fragments into LDS tiles (flat pitch 64): Bs<-Y, Cs<-Sdel ----
    ushort_t* Yt = (ushort_t*)Bs;
    ushort_t* St = (ushort_t*)Cs;
#pragma unroll
    for (int mi = 0; mi < 2; ++mi)
#pragma unroll
        for (int nj = 0; nj < 2; ++nj) {
#pragma unroll
            for (int r = 0; r < 4; ++r) {
                int i  = wr * 32 + mi * 16 + rg * 4 + r;   // time (Y) / hd (S)
                int jd = wc * 32 + nj * 16 + fr;           // hd (Y) / ds (S)
                St[i * 64 + jd] = f2bf(accs[mi][nj][r]);
                Yt[i * 64 + jd] = f2bf(accy[mi][nj][r]);
            }
        }
    __syncthreads();

    // ---- coalesced copy-out: 512 x 16B units each ----
    ushort_t* yout = dir ? ybw : yfw;
    ushort_t* sdp = sdel + (((size_t)bd * NHEADS_ + h) * 32 + c) * 4096;
    for (int un = tid; un < 512; un += 256) {
        const int rowi = un >> 3, ch = un & 7;
        uint4 sv = *reinterpret_cast<const uint4*>(St + rowi * 64 + ch * 8);
        *reinterpret_cast<uint4*>(sdp + rowi * 64 + ch * 8) = sv;
        uint4 yv = *reinterpret_cast<const uint4*>(Yt + rowi * 64 + ch * 8);
        int tau = c * 64 + rowi;
        int tout;
        if (tau == L_SEQ - 1) { tout = dir ? (L_SEQ - 1) : 0; yv = make_uint4(0, 0, 0, 0); }
        else                  { tout = dir ? (L_SEQ - 2 - tau) : (tau + 1); }
        *reinterpret_cast<uint4*>(yout + ((size_t)beta * L_SEQ + tout) * DINNER + h * 64 + ch * 8) = yv;
    }
}

// ---------------- SSD state scan: sdel (bf16, in-place) -> S_in prefix per chunk ------
__global__ __launch_bounds__(256)
void ssd_scan_kernel(const float* __restrict__ Pbuf, ushort_t* __restrict__ sdel) {
    const int bh = blockIdx.x;              // bd*NHEADS_ + h
    const int qt = blockIdx.y;              // state quarter
    const int eo = qt * 1024 + threadIdx.x * 4;
    ushort_t* base = sdel + (size_t)bh * 32 * 4096;
    const float* Pb = Pbuf + (size_t)bh * L_SEQ;

    float S0 = 0.f, S1 = 0.f, S2 = 0.f, S3 = 0.f;
    uint2 d = *reinterpret_cast<const uint2*>(base + eo);
    for (int c = 0; c < 32; ++c) {
        uint2 dn;
        if (c + 1 < 32) dn = *reinterpret_cast<const uint2*>(base + (size_t)(c + 1) * 4096 + eo);
        const float ptot = Pb[c * 64 + 63];
        uint2 pv;
        pv.x = (uint_t)f2bf(S0) | ((uint_t)f2bf(S1) << 16);
        pv.y = (uint_t)f2bf(S2) | ((uint_t)f2bf(S3) << 16);
        *reinterpret_cast<uint2*>(base + (size_t)c * 4096 + eo) = pv;
        S0 = ptot * S0 + bf2f((ushort_t)(d.x & 0xFFFF));
        S1 = ptot * S1 + bf2f((ushort_t)(d.x >> 16));
        S2 = ptot * S2 + bf2f((ushort_t)(d.y & 0xFFFF));
        S3 = ptot * S3 + bf2f((ushort_t)(d.y >> 16));
        d = dn;
    }
}

// ---------------- SSD Y_inter (chunk-parallel): y += P_i * (C @ S_in^T) ---------------
__global__ __launch_bounds__(256)
void ssd_yinter_kernel(const ushort_t* __restrict__ xBCbf, const float* __restrict__ Pbuf,
                       const ushort_t* __restrict__ sin_buf,
                       ushort_t* __restrict__ yfw, ushort_t* __restrict__ ybw) {
    const int c  = blockIdx.x;
    const int h  = blockIdx.y;
    const int bd = blockIdx.z;
    const int dir = bd >> 1, beta = bd & 1;
    const int tid = threadIdx.x;
    const int wave = tid >> 6, lane = tid & 63;
    const int fr = lane & 15, kg = lane >> 4, rg = lane >> 4;
    const int i0 = wave * 16;

    __shared__ short Cs[64 * PITCH], Ss[64 * PITCH];
    __shared__ float Pl[64];

    const int row = tid >> 2, seg = tid & 3;
    {
        const int tau_r = c * 64 + row;
        const int tt = dir ? (L_SEQ - 1 - tau_r) : tau_r;
        const ushort_t* gbase = xBCbf + ((size_t)beta * L_SEQ + tt) * CONVDIM + DINNER + dir * 128 + 64;
        uint4 cv0 = *reinterpret_cast<const uint4*>(gbase + seg * 16);
        uint4 cv1 = *reinterpret_cast<const uint4*>(gbase + seg * 16 + 8);
        *reinterpret_cast<uint4*>(&Cs[row * PITCH + seg * 16])     = cv0;
        *reinterpret_cast<uint4*>(&Cs[row * PITCH + seg * 16 + 8]) = cv1;
    }
    {
        const ushort_t* sb = sin_buf + (((size_t)bd * NHEADS_ + h) * 32 + c) * 4096;
        for (int un = tid; un < 512; un += 256) {
            const int ri = un >> 3, ch = un & 7;
            uint4 v = *reinterpret_cast<const uint4*>(sb + ri * 64 + ch * 8);
            *reinterpret_cast<uint4*>(&Ss[ri * PITCH + ch * 8]) = v;
        }
    }
    if (tid < 64) Pl[tid] = Pbuf[((size_t)bd * NHEADS_ + h) * L_SEQ + c * 64 + tid];
    __syncthreads();

    f32x4 accy[4];
#pragma unroll
    for (int nf = 0; nf < 4; ++nf) accy[nf] = (f32x4){0.f, 0.f, 0.f, 0.f};
#pragma unroll
    for (int s = 0; s < 2; ++s) {
        int koff = kg * 8 + s * 32;
        bf16x8 af = *reinterpret_cast<const bf16x8*>(&Cs[(i0 + fr) * PITCH + koff]);
#pragma unroll
        for (int nf = 0; nf < 4; ++nf) {
            bf16x8 bfv = *reinterpret_cast<const bf16x8*>(&Ss[(nf * 16 + fr) * PITCH + koff]);
            accy[nf] = __builtin_amdgcn_mfma_f32_16x16x32_bf16(af, bfv, accy[nf], 0, 0, 0);
        }
    }
    __syncthreads();

    ushort_t* Yt = (ushort_t*)Cs;
#pragma unroll
    for (int nf = 0; nf < 4; ++nf) {
        int hdl = nf * 16 + fr;
#pragma unroll
        for (int r = 0; r < 4; ++r) {
            int i = i0 + rg * 4 + r;
            Yt[i * 64 + hdl] = f2bf(accy[nf][r] * Pl[i]);
        }
    }
    __syncthreads();

    ushort_t* yout = dir ? ybw : yfw;
    for (int un = tid; un < 512; un += 256) {
        const int ri = un >> 3, ch = un & 7;
        int tau = c * 64 + ri;
        if (tau == L_SEQ - 1) continue;
        int tout = dir ? (L_SEQ - 2 - tau) : (tau + 1);
        ushort_t* gp = yout + ((size_t)beta * L_SEQ + tout) * DINNER + h * 64 + ch * 8;
        union U4 { uint4 v; ushort_t s[8]; } yo, cv, res;
        yo.v = *reinterpret_cast<const uint4*>(gp);
        cv.v = *reinterpret_cast<const uint4*>(Yt + ri * 64 + ch * 8);
#pragma unroll
        for (int k = 0; k < 8; ++k) res.s[k] = f2bf(bf2f(yo.s[k]) + bf2f(cv.s[k]));
        *reinterpret_cast<uint4*>(gp) = res.v;
    }
}

// ---------------- combine + RMSNorm + silu(z) gate -> bf16 y ---------------------------
__global__ __launch_bounds__(256)
void combine_rms(const ushort_t* __restrict__ yfw, const ushort_t* __restrict__ ybw,
                 const ushort_t* __restrict__ xBCbf, const float* __restrict__ dpart,
                 const float* __restrict__ Dp,
                 const ushort_t* __restrict__ zxbf, const float* __restrict__ norm_w,
                 ushort_t* __restrict__ ybf) {
    const int row = blockIdx.x;
    const int tid = threadIdx.x;
    union U4 { uint4 v; ushort_t s[8]; };
    U4 yf, yb, xv, zv;
    yf.v = *reinterpret_cast<const uint4*>(yfw + (size_t)row * DINNER + tid * 8);
    yb.v = *reinterpret_cast<const uint4*>(ybw + (size_t)row * DINNER + tid * 8);
    xv.v = *reinterpret_cast<const uint4*>(xBCbf + (size_t)row * CONVDIM + tid * 8);
    zv.v = *reinterpret_cast<const uint4*>(zxbf + (size_t)row * DINPROJ_P + tid * 8);
    const int hh = tid >> 3;
    float dgv = Dp[hh];
#pragma unroll
    for (int ks = 0; ks < KSPL; ++ks)
        dgv += dpart[((size_t)ks * (BATCH_ * L_SEQ) + row) * NHEADS_ + hh];
    float v[8];
    float ss = 0.f;
#pragma unroll
    for (int i = 0; i < 8; ++i) {
        float val = bf2f(yf.s[i]) + bf2f(yb.s[i]) + bf2f(xv.s[i]) * dgv;
        v[i] = val;
        ss += val * val;
    }
    ss += __shfl_xor(ss, 1);  ss += __shfl_xor(ss, 2);  ss += __shfl_xor(ss, 4);
    ss += __shfl_xor(ss, 8);  ss += __shfl_xor(ss, 16); ss += __shfl_xor(ss, 32);
    __shared__ float wsum[4];
    if ((tid & 63) == 0) wsum[tid >> 6] = ss;
    __syncthreads();
    ss = wsum[0] + wsum[1] + wsum[2] + wsum[3];
    const float inv = rsqrtf(ss * (1.f / DINNER) + EPS_);
    U4 outv;
#pragma unroll
    for (int i = 0; i < 8; ++i) {
        int c = tid * 8 + i;
        outv.s[i] = f2bf(norm_w[c] * v[i] * inv * silu_f(bf2f(zv.s[i])));
    }
    *reinterpret_cast<uint4*>(ybf + (size_t)row * DINNER + tid * 8) = outv.v;
}

extern "C" void kernel_launch(void* const* d_in, const int* in_sizes, int n_in,
                              void* d_out, int out_size, void* d_ws, size_t ws_size,
                              hipStream_t stream) {
    const float* u       = (const float*)d_in[0];
    const float* W_in    = (const float*)d_in[1];
    const float* conv_w  = (const float*)d_in[2];
    const float* conv_b  = (const float*)d_in[3];
    const float* dt_bias = (const float*)d_in[4];
    const float* A_log   = (const float*)d_in[5];
    const float* Dp      = (const float*)d_in[6];
    const float* fc_D_w  = (const float*)d_in[7];
    const float* norm_w  = (const float*)d_in[8];
    const float* W_out   = (const float*)d_in[9];
    float* out = (float*)d_out;

    const int ROWS = BATCH_ * L_SEQ;     // 4096
    // ---- workspace layout (~152 MB) ----
    ushort_t* zxbf  = (ushort_t*)d_ws;                            // 4096*4608 bf16
    ushort_t* xBCbf = zxbf  + (size_t)ROWS * DINPROJ_P;           // 4096*2304 bf16
    ushort_t* yfw   = xBCbf + (size_t)ROWS * CONVDIM;             // 4096*2048 bf16
    ushort_t* ybw   = yfw   + (size_t)ROWS * DINNER;              // 4096*2048 bf16
    float* dpart = (float*)(ybw + (size_t)ROWS * DINNER);         // 8*4096*32 f32
    float* labuf = dpart + (size_t)KSPL * ROWS * NHEADS_;         // 4*32*2048 f32
    float* Pbuf  = labuf + (size_t)4 * NHEADS_ * L_SEQ;           // 4*32*2048 f32
    ushort_t* sdel = (ushort_t*)(Pbuf + (size_t)4 * NHEADS_ * L_SEQ); // 4*32*32*64*64 bf16
    ushort_t* wobf = sdel + (size_t)4 * NHEADS_ * 32 * 64 * 64;   // 1024*2048 bf16
    ushort_t* fcdbf = wobf + (size_t)DMODEL * DINNER;             // 64*2048 bf16
    ushort_t* ubf  = fcdbf + (size_t)64 * DINNER;                 // 4096*1024 bf16
    ushort_t* wibf = ubf  + (size_t)ROWS * DMODEL;                // 4608*1024 bf16
    ushort_t* ybf  = ubf;   // reuse (ubf+wibf dead after gemm1)

    // 0. all dtype conversions in one launch
    const size_t total_units = N0U + N1U + N2U + N3U;
    cvt_all<<<(int)((total_units + 255) / 256), 256, 0, stream>>>(
        u, W_in, W_out, fc_D_w, ubf, wibf, wobf, fcdbf);

    // 1. in_proj GEMM: 8-phase 256x256 pipeline, counted vmcnt
    gemm_8ph<<<(ROWS / 256) * (DINPROJ_P / 256), 512, 0, stream>>>(
        ubf, wibf, zxbf, ROWS, DINPROJ_P, DMODEL, DINPROJ_P / 256);

    // 2. depthwise conv + SiLU -> bf16 xBC
    dim3 gc(CONVDIM / 256, L_SEQ / 16, BATCH_);
    conv_kernel<<<gc, 256, 0, stream>>>(zxbf, conv_w, conv_b, xBCbf);

    // 2b. log-decay precompute
    dtla_kernel<<<(4 * L_SEQ * NHEADS_) / 256, 256, 0, stream>>>(zxbf, dt_bias, A_log, labuf);

    // 3a. SSD chunk-parallel intra work (Y_intra -> yfw/ybw, S_delta -> sdel bf16)
    dim3 ga(32, NHEADS_, 4);
    ssd_chunk_kernel<<<ga, 256, 0, stream>>>(xBCbf, labuf, Pbuf, sdel, yfw, ybw);

    // 3b. element-wise state scan (sdel overwritten in place with S_in prefixes)
    dim3 gsn(4 * NHEADS_, 4);
    ssd_scan_kernel<<<gsn, 256, 0, stream>>>(Pbuf, sdel);

    // 3c. chunk-parallel Y_inter RMW into yfw/ybw
    dim3 gy(32, NHEADS_, 4);
    ssd_yinter_kernel<<<gy, 256, 0, stream>>>(xBCbf, Pbuf, sdel, yfw, ybw);

    // 4. diag heads: K-split MFMA GEMM -> dpart[KSPL][4096][32]
    gemm_nt_mfma<64, 64, 2, 2, 2, 2, 2><<<(ROWS / 64) * KSPL, 256, 0, stream>>>(
        xBCbf, fcdbf, dpart, nullptr, ROWS, 64, DINNER, CONVDIM, DINNER, KSPL);

    // 5. combine + RMS norm + gate -> bf16 (sums diag partials + Dp)
    combine_rms<<<ROWS, 256, 0, stream>>>(yfw, ybw, xBCbf, dpart, Dp, zxbf, norm_w, ybf);

    // 6. out_proj GEMM (128-tile template): out = y @ W_out^T
    gemm_nt_mfma<128, 64, 2, 2, 4, 2, 0><<<(ROWS / 128) * (DMODEL / 64), 256, 0, stream>>>(
        ybf, wobf, out, nullptr, ROWS, DMODEL, DINNER, DINNER, DINNER, DMODEL / 64);
}

// Round 16
// 214.354 us; speedup vs baseline: 1.0243x; 1.0243x over previous
//
#include <hip/hip_runtime.h>
#include <cstdint>
#include <cstddef>

#define L_SEQ   2048
#define DMODEL  1024
#define DINNER  2048
#define NHEADS_ 32
#define HEADDIM_ 64
#define DSTATE  64
#define CONVDIM 2304
#define DINPROJ 4416
#define DINPROJ_P 4608   // padded to 256-multiple for the 8-phase tile
#define BATCH_  2
#define EPS_    1e-5f
#define PITCH   72       // LDS tile pitch in bf16 elems (144B rows)
#define KSPL    8        // diag GEMM K-split

typedef __attribute__((ext_vector_type(8))) short bf16x8;
typedef __attribute__((ext_vector_type(4))) float f32x4;
typedef unsigned short ushort_t;
typedef unsigned int uint_t;
typedef __attribute__((address_space(3))) unsigned int as3_uint;
typedef __attribute__((address_space(1))) const unsigned int as1_uint;

__device__ __forceinline__ float silu_f(float v) { return v / (1.f + __expf(-v)); }
__device__ __forceinline__ ushort_t f2bf(float f) {
    uint_t u = __float_as_uint(f);
    return (ushort_t)((u + 0x7FFFu + ((u >> 16) & 1u)) >> 16);   // RNE
}
__device__ __forceinline__ float bf2f(ushort_t u) {
    return __uint_as_float(((uint_t)u) << 16);
}
__device__ __forceinline__ void gload16(const void* g, void* l) {
    __builtin_amdgcn_global_load_lds((as1_uint*)g, (as3_uint*)l, 16, 0, 0);
}

// ---------------- merged fp32 -> bf16 conversions (4 segments, 1 launch) --------------
#define N0U ((size_t)(4096 * 1024 / 4))          // u
#define N1U ((size_t)(DINPROJ_P * DMODEL / 4))   // W_in zero-padded to 4608 rows
#define N2U ((size_t)(DMODEL * DINNER / 4))      // W_out
#define N3U ((size_t)(64 * DINNER / 4))          // fc_D zero-padded
__global__ __launch_bounds__(256)
void cvt_all(const float* __restrict__ u, const float* __restrict__ W_in,
             const float* __restrict__ W_out, const float* __restrict__ fcD,
             ushort_t* __restrict__ ubf, ushort_t* __restrict__ wibf,
             ushort_t* __restrict__ wobf, ushort_t* __restrict__ fcdbf) {
    size_t unit = (size_t)blockIdx.x * 256 + threadIdx.x;
    if (unit >= N0U + N1U + N2U + N3U) return;
    const float* src; ushort_t* dst; size_t i4; bool zero = false;
    if (unit < N0U) {
        i4 = unit; src = u; dst = ubf;
    } else if (unit < N0U + N1U) {
        i4 = unit - N0U; src = W_in; dst = wibf;
        zero = ((int)(i4 / (DMODEL / 4)) >= DINPROJ);
    } else if (unit < N0U + N1U + N2U) {
        i4 = unit - N0U - N1U; src = W_out; dst = wobf;
    } else {
        i4 = unit - N0U - N1U - N2U; src = fcD; dst = fcdbf;
        zero = ((int)(i4 / (DINNER / 4)) >= NHEADS_);
    }
    float4 v = zero ? make_float4(0.f, 0.f, 0.f, 0.f)
                    : reinterpret_cast<const float4*>(src)[i4];
    ushort_t* d = dst + i4 * 4;
    d[0] = f2bf(v.x); d[1] = f2bf(v.y); d[2] = f2bf(v.z); d[3] = f2bf(v.w);
}

// ---------------- 8-phase 256x256 bf16 MFMA GEMM (gemm1) ------------------------------
// 512 threads = 8 waves (2x4). BK=64, 2 K-tiles/iter, 8 phases/iter. Stage-on-death.
// A-half reads extend to ph2/ph6 (mh=1), B-half reads end at ph1/ph5 -> stage order
// within each tile refill must be B0 THEN A0 (round-15 WAR race fix). vmcnt(6) at
// ph0/ph4 (counted); last-iteration ph4 drains with vmcnt(0) (round-14 tail fix).
__global__ __launch_bounds__(512, 2)
void gemm_8ph(const ushort_t* __restrict__ Ap, const ushort_t* __restrict__ Bp,
              ushort_t* __restrict__ Cbf, int M, int N, int K, int nbn) {
    const int nwg = gridDim.x;
    const int orig = blockIdx.x;
    const int xcd = orig & 7, q_ = nwg >> 3, r_ = nwg & 7;
    const int wg = ((xcd < r_) ? (xcd * (q_ + 1)) : (r_ * (q_ + 1) + (xcd - r_) * q_)) + (orig >> 3);
    const int bm = (wg / nbn) * 256, bn = (wg % nbn) * 256;

    __shared__ __align__(16) char smem[131072];   // 2 bufs x (A 32KB | B 32KB)

    const int tid = threadIdx.x;
    const int wave = tid >> 6, lane = tid & 63;
    const int wr = wave >> 2, wc = wave & 3;      // 2 x 4 wave grid
    const int fr = lane & 15, kg = lane >> 4, rg = lane >> 4;
    const int NT = K / 64;

    // one half-tile stage: 2 gload16/thread (rows half*128+wave*16 .. +16)
    const int rA = lane >> 3;
    const int slot = (lane & 7) ^ rA;             // pre-swizzled k-slot
    auto stage_half = [&](int pbuf, int isB, int half, int t) {
        if (t >= NT) return;
#pragma unroll
        for (int g = 0; g < 2; ++g) {
            int rbase = half * 128 + wave * 16 + g * 8;
            const ushort_t* src = (isB ? Bp : Ap)
                + (size_t)((isB ? bn : bm) + rbase + rA) * (size_t)K + slot * 8 + (size_t)t * 64;
            gload16(src, smem + pbuf * 65536 + isB * 32768 + rbase * 128);
        }
    };

    f32x4 acc[8][4];
#pragma unroll
    for (int m = 0; m < 8; ++m)
#pragma unroll
        for (int n = 0; n < 4; ++n) acc[m][n] = (f32x4){0.f, 0.f, 0.f, 0.f};

    bf16x8 aF[4][2];        // current A half frags
    bf16x8 bF[2][2][2];     // both B halves persist per tile

    auto lda_frag = [&](int pbuf, int mh) {
#pragma unroll
        for (int mm = 0; mm < 4; ++mm)
#pragma unroll
            for (int kk = 0; kk < 2; ++kk) {
                int Rl = wr * 128 + mh * 64 + mm * 16 + fr;
                aF[mm][kk] = *reinterpret_cast<const bf16x8*>(
                    smem + pbuf * 65536 + Rl * 128 + (((kk * 4 + kg) ^ (Rl & 7)) << 4));
            }
    };
    auto ldb_frag = [&](int pbuf, int nh) {
#pragma unroll
        for (int nn = 0; nn < 2; ++nn)
#pragma unroll
            for (int kk = 0; kk < 2; ++kk) {
                int Rl = wc * 64 + (nh * 2 + nn) * 16 + fr;
                bF[nh][nn][kk] = *reinterpret_cast<const bf16x8*>(
                    smem + pbuf * 65536 + 32768 + Rl * 128 + (((kk * 4 + kg) ^ (Rl & 7)) << 4));
            }
    };
    auto do_mfma = [&](int mh, int nh) {
        __builtin_amdgcn_s_setprio(1);
#pragma unroll
        for (int mm = 0; mm < 4; ++mm)
#pragma unroll
            for (int nn = 0; nn < 2; ++nn)
#pragma unroll
                for (int kk = 0; kk < 2; ++kk)
                    acc[mh * 4 + mm][nh * 2 + nn] = __builtin_amdgcn_mfma_f32_16x16x32_bf16(
                        aF[mm][kk], bF[nh][nn][kk], acc[mh * 4 + mm][nh * 2 + nn], 0, 0, 0);
        __builtin_amdgcn_s_setprio(0);
    };

    // ---- prologue: buf0 <- tile 0 (all 4 halves); buf1 <- A0,B0 of tile 1 ----
    stage_half(0, 0, 0, 0); stage_half(0, 1, 0, 0);
    stage_half(0, 0, 1, 0); stage_half(0, 1, 1, 0);
    stage_half(1, 0, 0, 1); stage_half(1, 1, 0, 1);
    asm volatile("s_waitcnt vmcnt(0)" ::: "memory");
    __builtin_amdgcn_sched_barrier(0);
    __builtin_amdgcn_s_barrier();

    const int NITER = NT / 2;
    for (int j = 0; j < NITER; ++j) {
        const int o = 2 * j + 1, e2 = 2 * j + 2, o2 = 2 * j + 3;
        // ---- ph0: tile e quadrant (0,0) ----
        stage_half(1, 0, 1, o);                  // buf1.A1 <- A1(o)
        asm volatile("s_waitcnt vmcnt(6)" ::: "memory");
        __builtin_amdgcn_sched_barrier(0);
        __builtin_amdgcn_s_barrier();            // buf0 tile-e halves landed
        lda_frag(0, 0); ldb_frag(0, 0);
        asm volatile("s_waitcnt lgkmcnt(0)" ::: "memory");
        __builtin_amdgcn_sched_barrier(0);
        do_mfma(0, 0);
        __builtin_amdgcn_s_barrier();
        // ---- ph1: (0,1) ----
        stage_half(1, 1, 1, o);                  // buf1.B1 <- B1(o)
        ldb_frag(0, 1);
        asm volatile("s_waitcnt lgkmcnt(0)" ::: "memory");
        __builtin_amdgcn_sched_barrier(0);
        do_mfma(0, 1);
        __builtin_amdgcn_s_barrier();
        // ---- ph2: (1,0) -- buf0.A still read here (mh=1), so stage B0 not A0 ----
        stage_half(0, 1, 0, e2);                 // buf0.B0 <- B0(e+2)  [B reads died ph1]
        lda_frag(0, 1);
        asm volatile("s_waitcnt lgkmcnt(0)" ::: "memory");
        __builtin_amdgcn_sched_barrier(0);
        do_mfma(1, 0);
        __builtin_amdgcn_s_barrier();
        // ---- ph3: (1,1) ----
        stage_half(0, 0, 0, e2);                 // buf0.A0 <- A0(e+2)  [A reads died ph2]
        do_mfma(1, 1);
        __builtin_amdgcn_s_barrier();
        // ---- ph4: tile o quadrant (0,0) ----
        stage_half(0, 0, 1, e2);                 // buf0.A1
        if (e2 < NT) {                           // pipeline full: counted wait
            asm volatile("s_waitcnt vmcnt(6)" ::: "memory");
        } else {                                 // tail: later stages skipped -> drain
            asm volatile("s_waitcnt vmcnt(0)" ::: "memory");
        }
        __builtin_amdgcn_sched_barrier(0);
        __builtin_amdgcn_s_barrier();            // buf1 tile-o halves landed
        lda_frag(1, 0); ldb_frag(1, 0);
        asm volatile("s_waitcnt lgkmcnt(0)" ::: "memory");
        __builtin_amdgcn_sched_barrier(0);
        do_mfma(0, 0);
        __builtin_amdgcn_s_barrier();
        // ---- ph5: (0,1) ----
        stage_half(0, 1, 1, e2);                 // buf0.B1
        ldb_frag(1, 1);
        asm volatile("s_waitcnt lgkmcnt(0)" ::: "memory");
        __builtin_amdgcn_sched_barrier(0);
        do_mfma(0, 1);
        __builtin_amdgcn_s_barrier();
        // ---- ph6: (1,0) -- buf1.A still read here, stage B0 not A0 ----
        stage_half(1, 1, 0, o2);                 // buf1.B0 <- B0(o+2)  [B reads died ph5]
        lda_frag(1, 1);
        asm volatile("s_waitcnt lgkmcnt(0)" ::: "memory");
        __builtin_amdgcn_sched_barrier(0);
        do_mfma(1, 0);
        __builtin_amdgcn_s_barrier();
        // ---- ph7: (1,1) ----
        stage_half(1, 0, 0, o2);                 // buf1.A0 <- A0(o+2)  [A reads died ph6]
        do_mfma(1, 1);
        __builtin_amdgcn_s_barrier();
    }
    asm volatile("s_waitcnt vmcnt(0)" ::: "memory");
    __builtin_amdgcn_sched_barrier(0);
    __builtin_amdgcn_s_barrier();

    // ---- epilogue: LDS-staged coalesced bf16 C-write (256x256 = 128KB) ----
    char* ct = smem;
#pragma unroll
    for (int m = 0; m < 8; ++m)
#pragma unroll
        for (int n = 0; n < 4; ++n) {
#pragma unroll
            for (int r = 0; r < 4; ++r) {
                int lr = wr * 128 + m * 16 + rg * 4 + r;
                int lc = wc * 64 + n * 16 + fr;
                int byte = lr * 512 + ((lc * 2) ^ ((lr & 7) << 4));
                *reinterpret_cast<ushort_t*>(ct + byte) = f2bf(acc[m][n][r]);
            }
        }
    __syncthreads();
    for (int pass = 0; pass < 16; ++pass) {
        int unit = pass * 512 + tid;               // 8192 units of 16B
        int row = unit >> 5, u = unit & 31;
        uint4 v = *reinterpret_cast<const uint4*>(ct + row * 512 + ((u * 16) ^ ((row & 7) << 4)));
        *reinterpret_cast<uint4*>(&Cbf[(size_t)(bm + row) * N + bn + u * 8]) = v;
    }
}

// ---------------- bf16 MFMA GEMM (128-tile template, gemm3 + diag) --------------------
template<int BM, int BN, int WGM, int WGN, int FM, int FN, int MODE>
__global__ __launch_bounds__(256)
void gemm_nt_mfma(const ushort_t* __restrict__ A, const ushort_t* __restrict__ B,
                  float* __restrict__ C, ushort_t* __restrict__ Cbf,
                  int M, int N, int K, int lda, int ldb, int nbn) {
    const int nwg = gridDim.x;
    const int orig = blockIdx.x;
    const int xcd = orig & 7, q = nwg >> 3, r = nwg & 7;
    const int wg = ((xcd < r) ? (xcd * (q + 1)) : (r * (q + 1) + (xcd - r) * q)) + (orig >> 3);

    int bm, bn, kbeg, kend, ks = 0;
    if (MODE == 2) {
        bm = (wg / nbn) * BM; bn = 0; ks = wg % nbn;
        kbeg = ks * (K / nbn); kend = kbeg + K / nbn;
    } else {
        bm = (wg / nbn) * BM; bn = (wg % nbn) * BN;
        kbeg = 0; kend = K;
    }

    constexpr int BUFSZ = (BM + BN) * 64;
    constexpr int EPI_B = (MODE == 2) ? 0 : BM * 256;
    constexpr int SMEM_B = (2 * BUFSZ > EPI_B) ? 2 * BUFSZ : EPI_B;
    __shared__ __align__(16) char smem[SMEM_B];

    const int tid = threadIdx.x;
    const int wave = tid >> 6, lane = tid & 63;
    const int wr = wave / WGN, wc = wave % WGN;
    const int fr = lane & 15, kg = lane >> 4;

    constexpr int AI = BM / 64, BI = BN / 64;
    size_t aoff[AI]; int aLds[AI];
#pragma unroll
    for (int pp = 0; pp < AI; ++pp) {
        int p = wave * AI + pp;
        int row = p * 16 + (lane >> 2);
        int c16 = (lane & 3) ^ ((row >> 1) & 3);
        aoff[pp] = (size_t)(bm + row) * lda + c16 * 8;
        aLds[pp] = p * 1024;
    }
    size_t boff[BI]; int bLds[BI];
#pragma unroll
    for (int pp = 0; pp < BI; ++pp) {
        int p = wave * BI + pp;
        int row = p * 16 + (lane >> 2);
        int c16 = (lane & 3) ^ ((row >> 1) & 3);
        boff[pp] = (size_t)(bn + row) * ldb + c16 * 8;
        bLds[pp] = BM * 64 + p * 1024;
    }

    auto stage = [&](int buf, int k0) {
        char* bp = smem + buf * BUFSZ;
#pragma unroll
        for (int pp = 0; pp < AI; ++pp) gload16(&A[aoff[pp] + k0], bp + aLds[pp]);
#pragma unroll
        for (int pp = 0; pp < BI; ++pp) gload16(&B[boff[pp] + k0], bp + bLds[pp]);
    };

    f32x4 acc[FM][FN];
#pragma unroll
    for (int m = 0; m < FM; ++m)
#pragma unroll
        for (int n = 0; n < FN; ++n) acc[m][n] = (f32x4){0.f, 0.f, 0.f, 0.f};

    stage(0, kbeg);
    __syncthreads();

    const int NT = (kend - kbeg) / 32;
    for (int t = 0; t < NT; ++t) {
        const int cur = t & 1;
        if (t + 1 < NT) stage(cur ^ 1, kbeg + (t + 1) * 32);

        const char* bp = smem + cur * BUFSZ;
        bf16x8 af[FM], bfv[FN];
#pragma unroll
        for (int m = 0; m < FM; ++m) {
            int row = wr * FM * 16 + m * 16 + fr;
            af[m] = *reinterpret_cast<const bf16x8*>(bp + row * 64 + ((kg ^ ((row >> 1) & 3)) << 4));
        }
#pragma unroll
        for (int n = 0; n < FN; ++n) {
            int row = wc * FN * 16 + n * 16 + fr;
            bfv[n] = *reinterpret_cast<const bf16x8*>(bp + BM * 64 + row * 64 + ((kg ^ ((row >> 1) & 3)) << 4));
        }
#pragma unroll
        for (int m = 0; m < FM; ++m)
#pragma unroll
            for (int n = 0; n < FN; ++n)
                acc[m][n] = __builtin_amdgcn_mfma_f32_16x16x32_bf16(af[m], bfv[n], acc[m][n], 0, 0, 0);
        __syncthreads();
    }

    const int rg = lane >> 4;
    if (MODE == 2) {
        float* Cp = C + (size_t)ks * M * NHEADS_;
#pragma unroll
        for (int m = 0; m < FM; ++m)
#pragma unroll
            for (int n = 0; n < FN; ++n) {
                int col = wc * FN * 16 + n * 16 + fr;
#pragma unroll
                for (int r = 0; r < 4; ++r) {
                    int rowg = bm + wr * FM * 16 + m * 16 + rg * 4 + r;
                    if (col < NHEADS_) Cp[(size_t)rowg * NHEADS_ + col] = acc[m][n][r];
                }
            }
    } else {
        char* ct = smem;
#pragma unroll
        for (int m = 0; m < FM; ++m)
#pragma unroll
            for (int n = 0; n < FN; ++n) {
#pragma unroll
                for (int r = 0; r < 4; ++r) {
                    int lr = wr * FM * 16 + m * 16 + rg * 4 + r;
                    int lc = wc * FN * 16 + n * 16 + fr;
                    int byte = (lr * 256 + lc * 4) ^ ((lr & 7) << 4);
                    *reinterpret_cast<float*>(ct + byte) = acc[m][n][r];
                }
            }
        __syncthreads();
        const int lrow = tid >> 4, seg16 = (tid & 15) * 16;
#pragma unroll
        for (int j = 0; j < BM / 16; ++j) {
            int lr = j * 16 + lrow;
            uint4 v = *reinterpret_cast<const uint4*>(ct + ((lr * 256 + seg16) ^ ((lr & 7) << 4)));
            *reinterpret_cast<uint4*>(&C[(size_t)(bm + lr) * N + bn + seg16 / 4]) = v;
        }
    }
}

// ---------------- depthwise conv + bias + SiLU -> bf16 xBC ----------------------------
__global__ __launch_bounds__(256)
void conv_kernel(const ushort_t* __restrict__ zxbf, const float* __restrict__ conv_w,
                 const float* __restrict__ conv_b, ushort_t* __restrict__ xBCbf) {
    const int c = blockIdx.x * 256 + threadIdx.x;   // channel 0..2303
    const int t0 = blockIdx.y * 16;
    const int beta = blockIdx.z;
    float w[7];
#pragma unroll
    for (int k = 0; k < 7; ++k) w[k] = conv_w[c * 7 + k];
    const float bias = conv_b[c];
    const ushort_t* in = zxbf + (size_t)beta * L_SEQ * DINPROJ_P + DINNER + c;
    float win[7];
#pragma unroll
    for (int j = 0; j < 6; ++j) {
        int t = t0 - 3 + j;
        win[j] = (t >= 0 && t < L_SEQ) ? bf2f(in[(size_t)t * DINPROJ_P]) : 0.f;
    }
    for (int i = 0; i < 16; ++i) {
        int t = t0 + i;
        int tl = t + 3;
        win[6] = (tl < L_SEQ) ? bf2f(in[(size_t)tl * DINPROJ_P]) : 0.f;
        float acc = bias;
#pragma unroll
        for (int k = 0; k < 7; ++k) acc += win[k] * w[k];
        xBCbf[((size_t)beta * L_SEQ + t) * CONVDIM + c] = f2bf(silu_f(acc));
#pragma unroll
        for (int j = 0; j < 6; ++j) win[j] = win[j + 1];
    }
}

// ---------------- log-decay precompute: la[bd][h][tau] = A_h * softplus(dt+bias) ------
__global__ __launch_bounds__(256)
void dtla_kernel(const ushort_t* __restrict__ zxbf, const float* __restrict__ dt_bias,
                 const float* __restrict__ A_log, float* __restrict__ labuf) {
    const int idx = blockIdx.x * 256 + threadIdx.x;     // 4*2048*32
    const int h   = idx & 31;
    const int tau = (idx >> 5) & (L_SEQ - 1);
    const int bd  = idx >> 16;
    const int dir = bd >> 1, beta = bd & 1;
    const int tt  = dir ? (L_SEQ - 1 - tau) : tau;
    const float dtraw = bf2f(zxbf[((size_t)beta * L_SEQ + tt) * DINPROJ_P + DINNER + CONVDIM + dir * NHEADS_ + h]);
    const float Ah = -__expf(A_log[h]);
    const float dtv = dtraw + dt_bias[h];
    const float sp = (dtv > 15.f) ? dtv : log1pf(__expf(dtv));
    labuf[((size_t)bd * NHEADS_ + h) * L_SEQ + tau] = Ah * sp;
}

// ---------------- SSD chunk kernel (K_A): chunk-parallel intra work --------------------
__global__ __launch_bounds__(256)
void ssd_chunk_kernel(const ushort_t* __restrict__ xBCbf, const float* __restrict__ labuf,
                      float* __restrict__ Pbuf, ushort_t* __restrict__ sdel,
                      ushort_t* __restrict__ yfw, ushort_t* __restrict__ ybw) {
    const int c  = blockIdx.x;
    const int h  = blockIdx.y;
    const int bd = blockIdx.z;
    const int dir = bd >> 1, beta = bd & 1;
    const int tid = threadIdx.x;
    const int wave = tid >> 6, lane = tid & 63;
    const int wr = wave >> 1, wc = wave & 1;
    const int fr = lane & 15, kg = lane >> 4, rg = lane >> 4;

    __shared__ short Bs[64 * PITCH], Cs[64 * PITCH], XTs[64 * PITCH],
                     BTs[64 * PITCH], Ms[64 * PITCH];
    __shared__ float lslds[64];

    const int row = tid >> 2, seg = tid & 3;
    const int tau_r = c * 64 + row;
    const int tt = dir ? (L_SEQ - 1 - tau_r) : tau_r;
    const ushort_t* gbase = xBCbf + ((size_t)beta * L_SEQ + tt) * CONVDIM;

    union U4 { uint4 v; ushort_t s[8]; };
    U4 x0, x1, b0, b1, c0, c1;
    x0.v = *reinterpret_cast<const uint4*>(gbase + h * 64 + seg * 16);
    x1.v = *reinterpret_cast<const uint4*>(gbase + h * 64 + seg * 16 + 8);
    b0.v = *reinterpret_cast<const uint4*>(gbase + DINNER + dir * 128 + seg * 16);
    b1.v = *reinterpret_cast<const uint4*>(gbase + DINNER + dir * 128 + seg * 16 + 8);
    c0.v = *reinterpret_cast<const uint4*>(gbase + DINNER + dir * 128 + 64 + seg * 16);
    c1.v = *reinterpret_cast<const uint4*>(gbase + DINNER + dir * 128 + 64 + seg * 16 + 8);

    *reinterpret_cast<uint4*>(&Bs[row * PITCH + seg * 16])     = b0.v;
    *reinterpret_cast<uint4*>(&Bs[row * PITCH + seg * 16 + 8]) = b1.v;
    *reinterpret_cast<uint4*>(&Cs[row * PITCH + seg * 16])     = c0.v;
    *reinterpret_cast<uint4*>(&Cs[row * PITCH + seg * 16 + 8]) = c1.v;
#pragma unroll
    for (int k = 0; k < 8; ++k) {
        XTs[(seg * 16 + k) * PITCH + row]     = x0.s[k];
        XTs[(seg * 16 + 8 + k) * PITCH + row] = x1.s[k];
    }

    if (tid < 64) {
        float v = labuf[((size_t)bd * NHEADS_ + h) * L_SEQ + c * 64 + tid];
#pragma unroll
        for (int d = 1; d < 64; d <<= 1) {
            float t = __shfl_up(v, d);
            if (lane >= d) v += t;
        }
        lslds[tid] = v;
        Pbuf[((size_t)bd * NHEADS_ + h) * L_SEQ + c * 64 + tid] = __expf(v);
    }
    __syncthreads();

    {
        const float wrow = __expf(lslds[63] - lslds[row]);
#pragma unroll
        for (int k = 0; k < 8; ++k) {
            BTs[(seg * 16 + k) * PITCH + row]     = (short)f2bf(bf2f(b0.s[k]) * wrow);
            BTs[(seg * 16 + 8 + k) * PITCH + row] = (short)f2bf(bf2f(b1.s[k]) * wrow);
        }
    }

    // ---- G = C @ B^T ----
    f32x4 accg[2][2];
#pragma unroll
    for (int mi = 0; mi < 2; ++mi)
#pragma unroll
        for (int nj = 0; nj < 2; ++nj) accg[mi][nj] = (f32x4){0.f, 0.f, 0.f, 0.f};
#pragma unroll
    for (int s = 0; s < 2; ++s) {
        int koff = kg * 8 + s * 32;
        bf16x8 af[2], bfv[2];
#pragma unroll
        for (int mi = 0; mi < 2; ++mi)
            af[mi] = *reinterpret_cast<const bf16x8*>(&Cs[(wr * 32 + mi * 16 + fr) * PITCH + koff]);
#pragma unroll
        for (int nj = 0; nj < 2; ++nj)
            bfv[nj] = *reinterpret_cast<const bf16x8*>(&Bs[(wc * 32 + nj * 16 + fr) * PITCH + koff]);
#pragma unroll
        for (int mi = 0; mi < 2; ++mi)
#pragma unroll
            for (int nj = 0; nj < 2; ++nj)
                accg[mi][nj] = __builtin_amdgcn_mfma_f32_16x16x32_bf16(af[mi], bfv[nj], accg[mi][nj], 0, 0, 0);
    }

    // ---- M = mask .* exp(ls_i - ls_j) .* G -> bf16 LDS ----
#pragma unroll
    for (int mi = 0; mi < 2; ++mi)
#pragma unroll
        for (int nj = 0; nj < 2; ++nj) {
            int j = wc * 32 + nj * 16 + fr;
            float lsj = lslds[j];
#pragma unroll
            for (int r = 0; r < 4; ++r) {
                int i = wr * 32 + mi * 16 + rg * 4 + r;
                float v = accg[mi][nj][r];
                v = (i >= j) ? v * __expf(lslds[i] - lsj) : 0.f;
                Ms[i * PITCH + j] = (short)f2bf(v);
            }
        }
    __syncthreads();

    // ---- Y_intra = M @ X ; S_delta = X^T @ Bw ----
    f32x4 accy[2][2], accs[2][2];
#pragma unroll
    for (int mi = 0; mi < 2; ++mi)
#pragma unroll
        for (int nj = 0; nj < 2; ++nj) {
            accy[mi][nj] = (f32x4){0.f, 0.f, 0.f, 0.f};
            accs[mi][nj] = (f32x4){0.f, 0.f, 0.f, 0.f};
        }
#pragma unroll
    for (int s = 0; s < 2; ++s) {
        int koff = kg * 8 + s * 32;
        bf16x8 am[2], axt[2], bxt[2], bbt[2];
#pragma unroll
        for (int mi = 0; mi < 2; ++mi) {
            am[mi]  = *reinterpret_cast<const bf16x8*>(&Ms[(wr * 32 + mi * 16 + fr) * PITCH + koff]);
            axt[mi] = *reinterpret_cast<const bf16x8*>(&XTs[(wr * 32 + mi * 16 + fr) * PITCH + koff]);
        }
#pragma unroll
        for (int nj = 0; nj < 2; ++nj) {
            bxt[nj] = *reinterpret_cast<const bf16x8*>(&XTs[(wc * 32 + nj * 16 + fr) * PITCH + koff]);
            bbt[nj] = *reinterpret_cast<const bf16x8*>(&BTs[(wc * 32 + nj * 16 + fr) * PITCH + koff]);
        }
#pragma unroll
        for (int mi = 0; mi < 2; ++mi)
#pragma unroll
            for (int nj = 0; nj < 2; ++nj) {
                accy[mi][nj] = __builtin_amdgcn_mfma_f32_16x16x32_bf16(am[mi], bxt[nj], accy[mi][nj], 0, 0, 0);
                accs[mi][nj] = __builtin_amdgcn_mfma_f32_16x16x32_bf16(axt[mi], bbt[nj], accs[mi][nj], 0, 0, 0);
            }
    }

    // ---- stage fragments into LDS tiles (flat pitch 64): Bs<-Y, Cs<-Sdel ----
    ushort_t* Yt = (ushort_t*)Bs;
    ushort_t* St = (ushort_t*)Cs;
#pragma unroll
    for (int mi = 0; mi < 2; ++mi)
#pragma unroll
        for (int nj = 0; nj < 2; ++nj) {
#pragma unroll
            for (int r = 0; r < 4; ++r) {
                int i  = wr * 32 + mi * 16 + rg * 4 + r;   // time (Y) / hd (S)
                int jd = wc * 32 + nj * 16 + fr;           // hd (Y) / ds (S)
                St[i * 64 + jd] = f2bf(accs[mi][nj][r]);
                Yt[i * 64 + jd] = f2bf(accy[mi][nj][r]);
            }
        }
    __syncthreads();

    // ---- coalesced copy-out: 512 x 16B units each ----
    ushort_t* yout = dir ? ybw : yfw;
    ushort_t* sdp = sdel + (((size_t)bd * NHEADS_ + h) * 32 + c) * 4096;
    for (int un = tid; un < 512; un += 256) {
        const int rowi = un >> 3, ch = un & 7;
        uint4 sv = *reinterpret_cast<const uint4*>(St + rowi * 64 + ch * 8);
        *reinterpret_cast<uint4*>(sdp + rowi * 64 + ch * 8) = sv;
        uint4 yv = *reinterpret_cast<const uint4*>(Yt + rowi * 64 + ch * 8);
        int tau = c * 64 + rowi;
        int tout;
        if (tau == L_SEQ - 1) { tout = dir ? (L_SEQ - 1) : 0; yv = make_uint4(0, 0, 0, 0); }
        else                  { tout = dir ? (L_SEQ - 2 - tau) : (tau + 1); }
        *reinterpret_cast<uint4*>(yout + ((size_t)beta * L_SEQ + tout) * DINNER + h * 64 + ch * 8) = yv;
    }
}

// ---------------- SSD state scan: sdel (bf16, in-place) -> S_in prefix per chunk ------
__global__ __launch_bounds__(256)
void ssd_scan_kernel(const float* __restrict__ Pbuf, ushort_t* __restrict__ sdel) {
    const int bh = blockIdx.x;              // bd*NHEADS_ + h
    const int qt = blockIdx.y;              // state quarter
    const int eo = qt * 1024 + threadIdx.x * 4;
    ushort_t* base = sdel + (size_t)bh * 32 * 4096;
    const float* Pb = Pbuf + (size_t)bh * L_SEQ;

    float S0 = 0.f, S1 = 0.f, S2 = 0.f, S3 = 0.f;
    uint2 d = *reinterpret_cast<const uint2*>(base + eo);
    for (int c = 0; c < 32; ++c) {
        uint2 dn;
        if (c + 1 < 32) dn = *reinterpret_cast<const uint2*>(base + (size_t)(c + 1) * 4096 + eo);
        const float ptot = Pb[c * 64 + 63];
        uint2 pv;
        pv.x = (uint_t)f2bf(S0) | ((uint_t)f2bf(S1) << 16);
        pv.y = (uint_t)f2bf(S2) | ((uint_t)f2bf(S3) << 16);
        *reinterpret_cast<uint2*>(base + (size_t)c * 4096 + eo) = pv;
        S0 = ptot * S0 + bf2f((ushort_t)(d.x & 0xFFFF));
        S1 = ptot * S1 + bf2f((ushort_t)(d.x >> 16));
        S2 = ptot * S2 + bf2f((ushort_t)(d.y & 0xFFFF));
        S3 = ptot * S3 + bf2f((ushort_t)(d.y >> 16));
        d = dn;
    }
}

// ---------------- SSD Y_inter (chunk-parallel): y += P_i * (C @ S_in^T) ---------------
__global__ __launch_bounds__(256)
void ssd_yinter_kernel(const ushort_t* __restrict__ xBCbf, const float* __restrict__ Pbuf,
                       const ushort_t* __restrict__ sin_buf,
                       ushort_t* __restrict__ yfw, ushort_t* __restrict__ ybw) {
    const int c  = blockIdx.x;
    const int h  = blockIdx.y;
    const int bd = blockIdx.z;
    const int dir = bd >> 1, beta = bd & 1;
    const int tid = threadIdx.x;
    const int wave = tid >> 6, lane = tid & 63;
    const int fr = lane & 15, kg = lane >> 4, rg = lane >> 4;
    const int i0 = wave * 16;

    __shared__ short Cs[64 * PITCH], Ss[64 * PITCH];
    __shared__ float Pl[64];

    const int row = tid >> 2, seg = tid & 3;
    {
        const int tau_r = c * 64 + row;
        const int tt = dir ? (L_SEQ - 1 - tau_r) : tau_r;
        const ushort_t* gbase = xBCbf + ((size_t)beta * L_SEQ + tt) * CONVDIM + DINNER + dir * 128 + 64;
        uint4 cv0 = *reinterpret_cast<const uint4*>(gbase + seg * 16);
        uint4 cv1 = *reinterpret_cast<const uint4*>(gbase + seg * 16 + 8);
        *reinterpret_cast<uint4*>(&Cs[row * PITCH + seg * 16])     = cv0;
        *reinterpret_cast<uint4*>(&Cs[row * PITCH + seg * 16 + 8]) = cv1;
    }
    {
        const ushort_t* sb = sin_buf + (((size_t)bd * NHEADS_ + h) * 32 + c) * 4096;
        for (int un = tid; un < 512; un += 256) {
            const int ri = un >> 3, ch = un & 7;
            uint4 v = *reinterpret_cast<const uint4*>(sb + ri * 64 + ch * 8);
            *reinterpret_cast<uint4*>(&Ss[ri * PITCH + ch * 8]) = v;
        }
    }
    if (tid < 64) Pl[tid] = Pbuf[((size_t)bd * NHEADS_ + h) * L_SEQ + c * 64 + tid];
    __syncthreads();

    f32x4 accy[4];
#pragma unroll
    for (int nf = 0; nf < 4; ++nf) accy[nf] = (f32x4){0.f, 0.f, 0.f, 0.f};
#pragma unroll
    for (int s = 0; s < 2; ++s) {
        int koff = kg * 8 + s * 32;
        bf16x8 af = *reinterpret_cast<const bf16x8*>(&Cs[(i0 + fr) * PITCH + koff]);
#pragma unroll
        for (int nf = 0; nf < 4; ++nf) {
            bf16x8 bfv = *reinterpret_cast<const bf16x8*>(&Ss[(nf * 16 + fr) * PITCH + koff]);
            accy[nf] = __builtin_amdgcn_mfma_f32_16x16x32_bf16(af, bfv, accy[nf], 0, 0, 0);
        }
    }
    __syncthreads();

    ushort_t* Yt = (ushort_t*)Cs;
#pragma unroll
    for (int nf = 0; nf < 4; ++nf) {
        int hdl = nf * 16 + fr;
#pragma unroll
        for (int r = 0; r < 4; ++r) {
            int i = i0 + rg * 4 + r;
            Yt[i * 64 + hdl] = f2bf(accy[nf][r] * Pl[i]);
        }
    }
    __syncthreads();

    ushort_t* yout = dir ? ybw : yfw;
    for (int un = tid; un < 512; un += 256) {
        const int ri = un >> 3, ch = un & 7;
        int tau = c * 64 + ri;
        if (tau == L_SEQ - 1) continue;
        int tout = dir ? (L_SEQ - 2 - tau) : (tau + 1);
        ushort_t* gp = yout + ((size_t)beta * L_SEQ + tout) * DINNER + h * 64 + ch * 8;
        union U4 { uint4 v; ushort_t s[8]; } yo, cv, res;
        yo.v = *reinterpret_cast<const uint4*>(gp);
        cv.v = *reinterpret_cast<const uint4*>(Yt + ri * 64 + ch * 8);
#pragma unroll
        for (int k = 0; k < 8; ++k) res.s[k] = f2bf(bf2f(yo.s[k]) + bf2f(cv.s[k]));
        *reinterpret_cast<uint4*>(gp) = res.v;
    }
}

// ---------------- combine + RMSNorm + silu(z) gate -> bf16 y ---------------------------
__global__ __launch_bounds__(256)
void combine_rms(const ushort_t* __restrict__ yfw, const ushort_t* __restrict__ ybw,
                 const ushort_t* __restrict__ xBCbf, const float* __restrict__ dpart,
                 const float* __restrict__ Dp,
                 const ushort_t* __restrict__ zxbf, const float* __restrict__ norm_w,
                 ushort_t* __restrict__ ybf) {
    const int row = blockIdx.x;
    const int tid = threadIdx.x;
    union U4 { uint4 v; ushort_t s[8]; };
    U4 yf, yb, xv, zv;
    yf.v = *reinterpret_cast<const uint4*>(yfw + (size_t)row * DINNER + tid * 8);
    yb.v = *reinterpret_cast<const uint4*>(ybw + (size_t)row * DINNER + tid * 8);
    xv.v = *reinterpret_cast<const uint4*>(xBCbf + (size_t)row * CONVDIM + tid * 8);
    zv.v = *reinterpret_cast<const uint4*>(zxbf + (size_t)row * DINPROJ_P + tid * 8);
    const int hh = tid >> 3;
    float dgv = Dp[hh];
#pragma unroll
    for (int ks = 0; ks < KSPL; ++ks)
        dgv += dpart[((size_t)ks * (BATCH_ * L_SEQ) + row) * NHEADS_ + hh];
    float v[8];
    float ss = 0.f;
#pragma unroll
    for (int i = 0; i < 8; ++i) {
        float val = bf2f(yf.s[i]) + bf2f(yb.s[i]) + bf2f(xv.s[i]) * dgv;
        v[i] = val;
        ss += val * val;
    }
    ss += __shfl_xor(ss, 1);  ss += __shfl_xor(ss, 2);  ss += __shfl_xor(ss, 4);
    ss += __shfl_xor(ss, 8);  ss += __shfl_xor(ss, 16); ss += __shfl_xor(ss, 32);
    __shared__ float wsum[4];
    if ((tid & 63) == 0) wsum[tid >> 6] = ss;
    __syncthreads();
    ss = wsum[0] + wsum[1] + wsum[2] + wsum[3];
    const float inv = rsqrtf(ss * (1.f / DINNER) + EPS_);
    U4 outv;
#pragma unroll
    for (int i = 0; i < 8; ++i) {
        int c = tid * 8 + i;
        outv.s[i] = f2bf(norm_w[c] * v[i] * inv * silu_f(bf2f(zv.s[i])));
    }
    *reinterpret_cast<uint4*>(ybf + (size_t)row * DINNER + tid * 8) = outv.v;
}

extern "C" void kernel_launch(void* const* d_in, const int* in_sizes, int n_in,
                              void* d_out, int out_size, void* d_ws, size_t ws_size,
                              hipStream_t stream) {
    const float* u       = (const float*)d_in[0];
    const float* W_in    = (const float*)d_in[1];
    const float* conv_w  = (const float*)d_in[2];
    const float* conv_b  = (const float*)d_in[3];
    const float* dt_bias = (const float*)d_in[4];
    const float* A_log   = (const float*)d_in[5];
    const float* Dp      = (const float*)d_in[6];
    const float* fc_D_w  = (const float*)d_in[7];
    const float* norm_w  = (const float*)d_in[8];
    const float* W_out   = (const float*)d_in[9];
    float* out = (float*)d_out;

    const int ROWS = BATCH_ * L_SEQ;     // 4096
    // ---- workspace layout (~152 MB) ----
    ushort_t* zxbf  = (ushort_t*)d_ws;                            // 4096*4608 bf16
    ushort_t* xBCbf = zxbf  + (size_t)ROWS * DINPROJ_P;           // 4096*2304 bf16
    ushort_t* yfw   = xBCbf + (size_t)ROWS * CONVDIM;             // 4096*2048 bf16
    ushort_t* ybw   = yfw   + (size_t)ROWS * DINNER;              // 4096*2048 bf16
    float* dpart = (float*)(ybw + (size_t)ROWS * DINNER);         // 8*4096*32 f32
    float* labuf = dpart + (size_t)KSPL * ROWS * NHEADS_;         // 4*32*2048 f32
    float* Pbuf  = labuf + (size_t)4 * NHEADS_ * L_SEQ;           // 4*32*2048 f32
    ushort_t* sdel = (ushort_t*)(Pbuf + (size_t)4 * NHEADS_ * L_SEQ); // 4*32*32*64*64 bf16
    ushort_t* wobf = sdel + (size_t)4 * NHEADS_ * 32 * 64 * 64;   // 1024*2048 bf16
    ushort_t* fcdbf = wobf + (size_t)DMODEL * DINNER;             // 64*2048 bf16
    ushort_t* ubf  = fcdbf + (size_t)64 * DINNER;                 // 4096*1024 bf16
    ushort_t* wibf = ubf  + (size_t)ROWS * DMODEL;                // 4608*1024 bf16
    ushort_t* ybf  = ubf;   // reuse (ubf+wibf dead after gemm1)

    // 0. all dtype conversions in one launch
    const size_t total_units = N0U + N1U + N2U + N3U;
    cvt_all<<<(int)((total_units + 255) / 256), 256, 0, stream>>>(
        u, W_in, W_out, fc_D_w, ubf, wibf, wobf, fcdbf);

    // 1. in_proj GEMM: 8-phase 256x256 pipeline (WAR stage-order + tail-drain fixed)
    gemm_8ph<<<(ROWS / 256) * (DINPROJ_P / 256), 512, 0, stream>>>(
        ubf, wibf, zxbf, ROWS, DINPROJ_P, DMODEL, DINPROJ_P / 256);

    // 2. depthwise conv + SiLU -> bf16 xBC
    dim3 gc(CONVDIM / 256, L_SEQ / 16, BATCH_);
    conv_kernel<<<gc, 256, 0, stream>>>(zxbf, conv_w, conv_b, xBCbf);

    // 2b. log-decay precompute
    dtla_kernel<<<(4 * L_SEQ * NHEADS_) / 256, 256, 0, stream>>>(zxbf, dt_bias, A_log, labuf);

    // 3a. SSD chunk-parallel intra work (Y_intra -> yfw/ybw, S_delta -> sdel bf16)
    dim3 ga(32, NHEADS_, 4);
    ssd_chunk_kernel<<<ga, 256, 0, stream>>>(xBCbf, labuf, Pbuf, sdel, yfw, ybw);

    // 3b. element-wise state scan (sdel overwritten in place with S_in prefixes)
    dim3 gsn(4 * NHEADS_, 4);
    ssd_scan_kernel<<<gsn, 256, 0, stream>>>(Pbuf, sdel);

    // 3c. chunk-parallel Y_inter RMW into yfw/ybw
    dim3 gy(32, NHEADS_, 4);
    ssd_yinter_kernel<<<gy, 256, 0, stream>>>(xBCbf, Pbuf, sdel, yfw, ybw);

    // 4. diag heads: K-split MFMA GEMM -> dpart[KSPL][4096][32]
    gemm_nt_mfma<64, 64, 2, 2, 2, 2, 2><<<(ROWS / 64) * KSPL, 256, 0, stream>>>(
        xBCbf, fcdbf, dpart, nullptr, ROWS, 64, DINNER, CONVDIM, DINNER, KSPL);

    // 5. combine + RMS norm + gate -> bf16 (sums diag partials + Dp)
    combine_rms<<<ROWS, 256, 0, stream>>>(yfw, ybw, xBCbf, dpart, Dp, zxbf, norm_w, ybf);

    // 6. out_proj GEMM (128-tile template): out = y @ W_out^T
    gemm_nt_mfma<128, 64, 2, 2, 4, 2, 0><<<(ROWS / 128) * (DMODEL / 64), 256, 0, stream>>>(
        ybf, wobf, out, nullptr, ROWS, DMODEL, DINNER, DINNER, DINNER, DMODEL / 64);
}

// Round 17
// 207.007 us; speedup vs baseline: 1.0606x; 1.0355x over previous
//
#include <hip/hip_runtime.h>
#include <cstdint>
#include <cstddef>

#define L_SEQ   2048
#define DMODEL  1024
#define DINNER  2048
#define NHEADS_ 32
#define HEADDIM_ 64
#define DSTATE  64
#define CONVDIM 2304
#define DINPROJ 4416
#define DINPROJ_P 4480   // padded to 128-multiple for MFMA tiles
#define BATCH_  2
#define EPS_    1e-5f
#define PITCH   72       // LDS tile pitch in bf16 elems (144B rows)
#define KSPL    8        // diag GEMM K-split

typedef __attribute__((ext_vector_type(8))) short bf16x8;
typedef __attribute__((ext_vector_type(4))) float f32x4;
typedef unsigned short ushort_t;
typedef unsigned int uint_t;
typedef __attribute__((address_space(3))) unsigned int as3_uint;
typedef __attribute__((address_space(1))) const unsigned int as1_uint;

__device__ __forceinline__ float silu_f(float v) { return v / (1.f + __expf(-v)); }
__device__ __forceinline__ ushort_t f2bf(float f) {
    uint_t u = __float_as_uint(f);
    return (ushort_t)((u + 0x7FFFu + ((u >> 16) & 1u)) >> 16);   // RNE
}
__device__ __forceinline__ float bf2f(ushort_t u) {
    return __uint_as_float(((uint_t)u) << 16);
}
__device__ __forceinline__ void gload16(const void* g, void* l) {
    __builtin_amdgcn_global_load_lds((as1_uint*)g, (as3_uint*)l, 16, 0, 0);
}

// ---------------- merged fp32 -> bf16 conversions (4 segments, 1 launch) --------------
#define N0U ((size_t)(4096 * 1024 / 4))          // u
#define N1U ((size_t)(DINPROJ_P * DMODEL / 4))   // W_in zero-padded
#define N2U ((size_t)(DMODEL * DINNER / 4))      // W_out
#define N3U ((size_t)(64 * DINNER / 4))          // fc_D zero-padded
__global__ __launch_bounds__(256)
void cvt_all(const float* __restrict__ u, const float* __restrict__ W_in,
             const float* __restrict__ W_out, const float* __restrict__ fcD,
             ushort_t* __restrict__ ubf, ushort_t* __restrict__ wibf,
             ushort_t* __restrict__ wobf, ushort_t* __restrict__ fcdbf) {
    size_t unit = (size_t)blockIdx.x * 256 + threadIdx.x;
    if (unit >= N0U + N1U + N2U + N3U) return;
    const float* src; ushort_t* dst; size_t i4; bool zero = false;
    if (unit < N0U) {
        i4 = unit; src = u; dst = ubf;
    } else if (unit < N0U + N1U) {
        i4 = unit - N0U; src = W_in; dst = wibf;
        zero = ((int)(i4 / (DMODEL / 4)) >= DINPROJ);
    } else if (unit < N0U + N1U + N2U) {
        i4 = unit - N0U - N1U; src = W_out; dst = wobf;
    } else {
        i4 = unit - N0U - N1U - N2U; src = fcD; dst = fcdbf;
        zero = ((int)(i4 / (DINNER / 4)) >= NHEADS_);
    }
    float4 v = zero ? make_float4(0.f, 0.f, 0.f, 0.f)
                    : reinterpret_cast<const float4*>(src)[i4];
    ushort_t* d = dst + i4 * 4;
    d[0] = f2bf(v.x); d[1] = f2bf(v.y); d[2] = f2bf(v.z); d[3] = f2bf(v.w);
}

// ---------------- bf16 MFMA GEMM: C = A[M][K](lda) * B[N][K](ldb)^T -------------------
// global_load_lds(16B) staging, double-buffered; linear LDS dest with pre-swizzled
// global source. 1D grid with bijective XCD swizzle.
// MODE 0: fp32 C, LDS epilogue. MODE 1: bf16 C, LDS epilogue. MODE 2: K-split partials.
template<int BM, int BN, int WGM, int WGN, int FM, int FN, int MODE>
__global__ __launch_bounds__(256)
void gemm_nt_mfma(const ushort_t* __restrict__ A, const ushort_t* __restrict__ B,
                  float* __restrict__ C, ushort_t* __restrict__ Cbf,
                  int M, int N, int K, int lda, int ldb, int nbn) {
    const int nwg = gridDim.x;
    const int orig = blockIdx.x;
    const int xcd = orig & 7, q = nwg >> 3, r = nwg & 7;
    const int wg = ((xcd < r) ? (xcd * (q + 1)) : (r * (q + 1) + (xcd - r) * q)) + (orig >> 3);

    int bm, bn, kbeg, kend, ks = 0;
    if (MODE == 2) {
        bm = (wg / nbn) * BM; bn = 0; ks = wg % nbn;
        kbeg = ks * (K / nbn); kend = kbeg + K / nbn;
    } else {
        bm = (wg / nbn) * BM; bn = (wg % nbn) * BN;
        kbeg = 0; kend = K;
    }

    constexpr int BUFSZ = (BM + BN) * 64;
    constexpr int EPI_B = (MODE == 2) ? 0 : BM * 256;
    constexpr int SMEM_B = (2 * BUFSZ > EPI_B) ? 2 * BUFSZ : EPI_B;
    __shared__ __align__(16) char smem[SMEM_B];

    const int tid = threadIdx.x;
    const int wave = tid >> 6, lane = tid & 63;
    const int wr = wave / WGN, wc = wave % WGN;
    const int fr = lane & 15, kg = lane >> 4;

    constexpr int AI = BM / 64, BI = BN / 64;
    size_t aoff[AI]; int aLds[AI];
#pragma unroll
    for (int pp = 0; pp < AI; ++pp) {
        int p = wave * AI + pp;
        int row = p * 16 + (lane >> 2);
        int c16 = (lane & 3) ^ ((row >> 1) & 3);
        aoff[pp] = (size_t)(bm + row) * lda + c16 * 8;
        aLds[pp] = p * 1024;
    }
    size_t boff[BI]; int bLds[BI];
#pragma unroll
    for (int pp = 0; pp < BI; ++pp) {
        int p = wave * BI + pp;
        int row = p * 16 + (lane >> 2);
        int c16 = (lane & 3) ^ ((row >> 1) & 3);
        boff[pp] = (size_t)(bn + row) * ldb + c16 * 8;
        bLds[pp] = BM * 64 + p * 1024;
    }

    auto stage = [&](int buf, int k0) {
        char* bp = smem + buf * BUFSZ;
#pragma unroll
        for (int pp = 0; pp < AI; ++pp) gload16(&A[aoff[pp] + k0], bp + aLds[pp]);
#pragma unroll
        for (int pp = 0; pp < BI; ++pp) gload16(&B[boff[pp] + k0], bp + bLds[pp]);
    };

    f32x4 acc[FM][FN];
#pragma unroll
    for (int m = 0; m < FM; ++m)
#pragma unroll
        for (int n = 0; n < FN; ++n) acc[m][n] = (f32x4){0.f, 0.f, 0.f, 0.f};

    stage(0, kbeg);
    __syncthreads();

    const int NT = (kend - kbeg) / 32;
    for (int t = 0; t < NT; ++t) {
        const int cur = t & 1;
        if (t + 1 < NT) stage(cur ^ 1, kbeg + (t + 1) * 32);

        const char* bp = smem + cur * BUFSZ;
        bf16x8 af[FM], bfv[FN];
#pragma unroll
        for (int m = 0; m < FM; ++m) {
            int row = wr * FM * 16 + m * 16 + fr;
            af[m] = *reinterpret_cast<const bf16x8*>(bp + row * 64 + ((kg ^ ((row >> 1) & 3)) << 4));
        }
#pragma unroll
        for (int n = 0; n < FN; ++n) {
            int row = wc * FN * 16 + n * 16 + fr;
            bfv[n] = *reinterpret_cast<const bf16x8*>(bp + BM * 64 + row * 64 + ((kg ^ ((row >> 1) & 3)) << 4));
        }
#pragma unroll
        for (int m = 0; m < FM; ++m)
#pragma unroll
            for (int n = 0; n < FN; ++n)
                acc[m][n] = __builtin_amdgcn_mfma_f32_16x16x32_bf16(af[m], bfv[n], acc[m][n], 0, 0, 0);
        __syncthreads();
    }

    const int rg = lane >> 4;
    if (MODE == 2) {
        float* Cp = C + (size_t)ks * M * NHEADS_;
#pragma unroll
        for (int m = 0; m < FM; ++m)
#pragma unroll
            for (int n = 0; n < FN; ++n) {
                int col = wc * FN * 16 + n * 16 + fr;
#pragma unroll
                for (int r = 0; r < 4; ++r) {
                    int rowg = bm + wr * FM * 16 + m * 16 + rg * 4 + r;
                    if (col < NHEADS_) Cp[(size_t)rowg * NHEADS_ + col] = acc[m][n][r];
                }
            }
    } else {
        constexpr int ESZ = (MODE == 1) ? 2 : 4;
        char* ct = smem;
#pragma unroll
        for (int m = 0; m < FM; ++m)
#pragma unroll
            for (int n = 0; n < FN; ++n) {
#pragma unroll
                for (int r = 0; r < 4; ++r) {
                    int lr = wr * FM * 16 + m * 16 + rg * 4 + r;
                    int lc = wc * FN * 16 + n * 16 + fr;
                    int byte = (lr * 256 + lc * ESZ) ^ ((lr & 7) << 4);
                    if (MODE == 1) *reinterpret_cast<ushort_t*>(ct + byte) = f2bf(acc[m][n][r]);
                    else           *reinterpret_cast<float*>(ct + byte) = acc[m][n][r];
                }
            }
        __syncthreads();
        const int lrow = tid >> 4, seg16 = (tid & 15) * 16;
#pragma unroll
        for (int j = 0; j < BM / 16; ++j) {
            int lr = j * 16 + lrow;
            uint4 v = *reinterpret_cast<const uint4*>(ct + ((lr * 256 + seg16) ^ ((lr & 7) << 4)));
            if (MODE == 1)
                *reinterpret_cast<uint4*>(&Cbf[(size_t)(bm + lr) * N + bn + seg16 / 2]) = v;
            else
                *reinterpret_cast<uint4*>(&C[(size_t)(bm + lr) * N + bn + seg16 / 4]) = v;
        }
    }
}

// ---------------- depthwise conv + bias + SiLU -> bf16 xBC ----------------------------
__global__ __launch_bounds__(256)
void conv_kernel(const ushort_t* __restrict__ zxbf, const float* __restrict__ conv_w,
                 const float* __restrict__ conv_b, ushort_t* __restrict__ xBCbf) {
    const int c = blockIdx.x * 256 + threadIdx.x;   // channel 0..2303
    const int t0 = blockIdx.y * 16;
    const int beta = blockIdx.z;
    float w[7];
#pragma unroll
    for (int k = 0; k < 7; ++k) w[k] = conv_w[c * 7 + k];
    const float bias = conv_b[c];
    const ushort_t* in = zxbf + (size_t)beta * L_SEQ * DINPROJ_P + DINNER + c;
    float win[7];
#pragma unroll
    for (int j = 0; j < 6; ++j) {
        int t = t0 - 3 + j;
        win[j] = (t >= 0 && t < L_SEQ) ? bf2f(in[(size_t)t * DINPROJ_P]) : 0.f;
    }
    for (int i = 0; i < 16; ++i) {
        int t = t0 + i;
        int tl = t + 3;
        win[6] = (tl < L_SEQ) ? bf2f(in[(size_t)tl * DINPROJ_P]) : 0.f;
        float acc = bias;
#pragma unroll
        for (int k = 0; k < 7; ++k) acc += win[k] * w[k];
        xBCbf[((size_t)beta * L_SEQ + t) * CONVDIM + c] = f2bf(silu_f(acc));
#pragma unroll
        for (int j = 0; j < 6; ++j) win[j] = win[j + 1];
    }
}

// ---------------- log-decay precompute: la[bd][h][tau] = A_h * softplus(dt+bias) ------
__global__ __launch_bounds__(256)
void dtla_kernel(const ushort_t* __restrict__ zxbf, const float* __restrict__ dt_bias,
                 const float* __restrict__ A_log, float* __restrict__ labuf) {
    const int idx = blockIdx.x * 256 + threadIdx.x;     // 4*2048*32
    const int h   = idx & 31;
    const int tau = (idx >> 5) & (L_SEQ - 1);
    const int bd  = idx >> 16;
    const int dir = bd >> 1, beta = bd & 1;
    const int tt  = dir ? (L_SEQ - 1 - tau) : tau;
    const float dtraw = bf2f(zxbf[((size_t)beta * L_SEQ + tt) * DINPROJ_P + DINNER + CONVDIM + dir * NHEADS_ + h]);
    const float Ah = -__expf(A_log[h]);
    const float dtv = dtraw + dt_bias[h];
    const float sp = (dtv > 15.f) ? dtv : log1pf(__expf(dtv));
    labuf[((size_t)bd * NHEADS_ + h) * L_SEQ + tau] = Ah * sp;
}

// ---------------- SSD chunk kernel (K_A): chunk-parallel intra work --------------------
__global__ __launch_bounds__(256)
void ssd_chunk_kernel(const ushort_t* __restrict__ xBCbf, const float* __restrict__ labuf,
                      float* __restrict__ Pbuf, ushort_t* __restrict__ sdel,
                      ushort_t* __restrict__ yfw, ushort_t* __restrict__ ybw) {
    const int c  = blockIdx.x;
    const int h  = blockIdx.y;
    const int bd = blockIdx.z;
    const int dir = bd >> 1, beta = bd & 1;
    const int tid = threadIdx.x;
    const int wave = tid >> 6, lane = tid & 63;
    const int wr = wave >> 1, wc = wave & 1;
    const int fr = lane & 15, kg = lane >> 4, rg = lane >> 4;

    __shared__ short Bs[64 * PITCH], Cs[64 * PITCH], XTs[64 * PITCH],
                     BTs[64 * PITCH], Ms[64 * PITCH];
    __shared__ float lslds[64];

    const int row = tid >> 2, seg = tid & 3;
    const int tau_r = c * 64 + row;
    const int tt = dir ? (L_SEQ - 1 - tau_r) : tau_r;
    const ushort_t* gbase = xBCbf + ((size_t)beta * L_SEQ + tt) * CONVDIM;

    union U4 { uint4 v; ushort_t s[8]; };
    U4 x0, x1, b0, b1, c0, c1;
    x0.v = *reinterpret_cast<const uint4*>(gbase + h * 64 + seg * 16);
    x1.v = *reinterpret_cast<const uint4*>(gbase + h * 64 + seg * 16 + 8);
    b0.v = *reinterpret_cast<const uint4*>(gbase + DINNER + dir * 128 + seg * 16);
    b1.v = *reinterpret_cast<const uint4*>(gbase + DINNER + dir * 128 + seg * 16 + 8);
    c0.v = *reinterpret_cast<const uint4*>(gbase + DINNER + dir * 128 + 64 + seg * 16);
    c1.v = *reinterpret_cast<const uint4*>(gbase + DINNER + dir * 128 + 64 + seg * 16 + 8);

    *reinterpret_cast<uint4*>(&Bs[row * PITCH + seg * 16])     = b0.v;
    *reinterpret_cast<uint4*>(&Bs[row * PITCH + seg * 16 + 8]) = b1.v;
    *reinterpret_cast<uint4*>(&Cs[row * PITCH + seg * 16])     = c0.v;
    *reinterpret_cast<uint4*>(&Cs[row * PITCH + seg * 16 + 8]) = c1.v;
#pragma unroll
    for (int k = 0; k < 8; ++k) {
        XTs[(seg * 16 + k) * PITCH + row]     = x0.s[k];
        XTs[(seg * 16 + 8 + k) * PITCH + row] = x1.s[k];
    }

    if (tid < 64) {
        float v = labuf[((size_t)bd * NHEADS_ + h) * L_SEQ + c * 64 + tid];
#pragma unroll
        for (int d = 1; d < 64; d <<= 1) {
            float t = __shfl_up(v, d);
            if (lane >= d) v += t;
        }
        lslds[tid] = v;
        Pbuf[((size_t)bd * NHEADS_ + h) * L_SEQ + c * 64 + tid] = __expf(v);
    }
    __syncthreads();

    {
        const float wrow = __expf(lslds[63] - lslds[row]);
#pragma unroll
        for (int k = 0; k < 8; ++k) {
            BTs[(seg * 16 + k) * PITCH + row]     = (short)f2bf(bf2f(b0.s[k]) * wrow);
            BTs[(seg * 16 + 8 + k) * PITCH + row] = (short)f2bf(bf2f(b1.s[k]) * wrow);
        }
    }

    // ---- G = C @ B^T ----
    f32x4 accg[2][2];
#pragma unroll
    for (int mi = 0; mi < 2; ++mi)
#pragma unroll
        for (int nj = 0; nj < 2; ++nj) accg[mi][nj] = (f32x4){0.f, 0.f, 0.f, 0.f};
#pragma unroll
    for (int s = 0; s < 2; ++s) {
        int koff = kg * 8 + s * 32;
        bf16x8 af[2], bfv[2];
#pragma unroll
        for (int mi = 0; mi < 2; ++mi)
            af[mi] = *reinterpret_cast<const bf16x8*>(&Cs[(wr * 32 + mi * 16 + fr) * PITCH + koff]);
#pragma unroll
        for (int nj = 0; nj < 2; ++nj)
            bfv[nj] = *reinterpret_cast<const bf16x8*>(&Bs[(wc * 32 + nj * 16 + fr) * PITCH + koff]);
#pragma unroll
        for (int mi = 0; mi < 2; ++mi)
#pragma unroll
            for (int nj = 0; nj < 2; ++nj)
                accg[mi][nj] = __builtin_amdgcn_mfma_f32_16x16x32_bf16(af[mi], bfv[nj], accg[mi][nj], 0, 0, 0);
    }

    // ---- M = mask .* exp(ls_i - ls_j) .* G -> bf16 LDS ----
#pragma unroll
    for (int mi = 0; mi < 2; ++mi)
#pragma unroll
        for (int nj = 0; nj < 2; ++nj) {
            int j = wc * 32 + nj * 16 + fr;
            float lsj = lslds[j];
#pragma unroll
            for (int r = 0; r < 4; ++r) {
                int i = wr * 32 + mi * 16 + rg * 4 + r;
                float v = accg[mi][nj][r];
                v = (i >= j) ? v * __expf(lslds[i] - lsj) : 0.f;
                Ms[i * PITCH + j] = (short)f2bf(v);
            }
        }
    __syncthreads();

    // ---- Y_intra = M @ X ; S_delta = X^T @ Bw ----
    f32x4 accy[2][2], accs[2][2];
#pragma unroll
    for (int mi = 0; mi < 2; ++mi)
#pragma unroll
        for (int nj = 0; nj < 2; ++nj) {
            accy[mi][nj] = (f32x4){0.f, 0.f, 0.f, 0.f};
            accs[mi][nj] = (f32x4){0.f, 0.f, 0.f, 0.f};
        }
#pragma unroll
    for (int s = 0; s < 2; ++s) {
        int koff = kg * 8 + s * 32;
        bf16x8 am[2], axt[2], bxt[2], bbt[2];
#pragma unroll
        for (int mi = 0; mi < 2; ++mi) {
            am[mi]  = *reinterpret_cast<const bf16x8*>(&Ms[(wr * 32 + mi * 16 + fr) * PITCH + koff]);
            axt[mi] = *reinterpret_cast<const bf16x8*>(&XTs[(wr * 32 + mi * 16 + fr) * PITCH + koff]);
        }
#pragma unroll
        for (int nj = 0; nj < 2; ++nj) {
            bxt[nj] = *reinterpret_cast<const bf16x8*>(&XTs[(wc * 32 + nj * 16 + fr) * PITCH + koff]);
            bbt[nj] = *reinterpret_cast<const bf16x8*>(&BTs[(wc * 32 + nj * 16 + fr) * PITCH + koff]);
        }
#pragma unroll
        for (int mi = 0; mi < 2; ++mi)
#pragma unroll
            for (int nj = 0; nj < 2; ++nj) {
                accy[mi][nj] = __builtin_amdgcn_mfma_f32_16x16x32_bf16(am[mi], bxt[nj], accy[mi][nj], 0, 0, 0);
                accs[mi][nj] = __builtin_amdgcn_mfma_f32_16x16x32_bf16(axt[mi], bbt[nj], accs[mi][nj], 0, 0, 0);
            }
    }

    // ---- stage fragments into LDS tiles (flat pitch 64): Bs<-Y, Cs<-Sdel ----
    ushort_t* Yt = (ushort_t*)Bs;
    ushort_t* St = (ushort_t*)Cs;
#pragma unroll
    for (int mi = 0; mi < 2; ++mi)
#pragma unroll
        for (int nj = 0; nj < 2; ++nj) {
#pragma unroll
            for (int r = 0; r < 4; ++r) {
                int i  = wr * 32 + mi * 16 + rg * 4 + r;   // time (Y) / hd (S)
                int jd = wc * 32 + nj * 16 + fr;           // hd (Y) / ds (S)
                St[i * 64 + jd] = f2bf(accs[mi][nj][r]);
                Yt[i * 64 + jd] = f2bf(accy[mi][nj][r]);
            }
        }
    __syncthreads();

    // ---- coalesced copy-out: 512 x 16B units each ----
    ushort_t* yout = dir ? ybw : yfw;
    ushort_t* sdp = sdel + (((size_t)bd * NHEADS_ + h) * 32 + c) * 4096;
    for (int un = tid; un < 512; un += 256) {
        const int rowi = un >> 3, ch = un & 7;
        uint4 sv = *reinterpret_cast<const uint4*>(St + rowi * 64 + ch * 8);
        *reinterpret_cast<uint4*>(sdp + rowi * 64 + ch * 8) = sv;
        uint4 yv = *reinterpret_cast<const uint4*>(Yt + rowi * 64 + ch * 8);
        int tau = c * 64 + rowi;
        int tout;
        if (tau == L_SEQ - 1) { tout = dir ? (L_SEQ - 1) : 0; yv = make_uint4(0, 0, 0, 0); }
        else                  { tout = dir ? (L_SEQ - 2 - tau) : (tau + 1); }
        *reinterpret_cast<uint4*>(yout + ((size_t)beta * L_SEQ + tout) * DINNER + h * 64 + ch * 8) = yv;
    }
}

// ---------------- SSD state scan: sdel (bf16, in-place) -> S_in prefix per chunk ------
__global__ __launch_bounds__(256)
void ssd_scan_kernel(const float* __restrict__ Pbuf, ushort_t* __restrict__ sdel) {
    const int bh = blockIdx.x;              // bd*NHEADS_ + h
    const int qt = blockIdx.y;              // state quarter
    const int eo = qt * 1024 + threadIdx.x * 4;
    ushort_t* base = sdel + (size_t)bh * 32 * 4096;
    const float* Pb = Pbuf + (size_t)bh * L_SEQ;

    float S0 = 0.f, S1 = 0.f, S2 = 0.f, S3 = 0.f;
    uint2 d = *reinterpret_cast<const uint2*>(base + eo);
    for (int c = 0; c < 32; ++c) {
        uint2 dn;
        if (c + 1 < 32) dn = *reinterpret_cast<const uint2*>(base + (size_t)(c + 1) * 4096 + eo);
        const float ptot = Pb[c * 64 + 63];
        uint2 pv;
        pv.x = (uint_t)f2bf(S0) | ((uint_t)f2bf(S1) << 16);
        pv.y = (uint_t)f2bf(S2) | ((uint_t)f2bf(S3) << 16);
        *reinterpret_cast<uint2*>(base + (size_t)c * 4096 + eo) = pv;
        S0 = ptot * S0 + bf2f((ushort_t)(d.x & 0xFFFF));
        S1 = ptot * S1 + bf2f((ushort_t)(d.x >> 16));
        S2 = ptot * S2 + bf2f((ushort_t)(d.y & 0xFFFF));
        S3 = ptot * S3 + bf2f((ushort_t)(d.y >> 16));
        d = dn;
    }
}

// ---------------- SSD Y_inter (chunk-parallel): y += P_i * (C @ S_in^T) ---------------
__global__ __launch_bounds__(256)
void ssd_yinter_kernel(const ushort_t* __restrict__ xBCbf, const float* __restrict__ Pbuf,
                       const ushort_t* __restrict__ sin_buf,
                       ushort_t* __restrict__ yfw, ushort_t* __restrict__ ybw) {
    const int c  = blockIdx.x;
    const int h  = blockIdx.y;
    const int bd = blockIdx.z;
    const int dir = bd >> 1, beta = bd & 1;
    const int tid = threadIdx.x;
    const int wave = tid >> 6, lane = tid & 63;
    const int fr = lane & 15, kg = lane >> 4, rg = lane >> 4;
    const int i0 = wave * 16;

    __shared__ short Cs[64 * PITCH], Ss[64 * PITCH];
    __shared__ float Pl[64];

    const int row = tid >> 2, seg = tid & 3;
    {
        const int tau_r = c * 64 + row;
        const int tt = dir ? (L_SEQ - 1 - tau_r) : tau_r;
        const ushort_t* gbase = xBCbf + ((size_t)beta * L_SEQ + tt) * CONVDIM + DINNER + dir * 128 + 64;
        uint4 cv0 = *reinterpret_cast<const uint4*>(gbase + seg * 16);
        uint4 cv1 = *reinterpret_cast<const uint4*>(gbase + seg * 16 + 8);
        *reinterpret_cast<uint4*>(&Cs[row * PITCH + seg * 16])     = cv0;
        *reinterpret_cast<uint4*>(&Cs[row * PITCH + seg * 16 + 8]) = cv1;
    }
    {
        const ushort_t* sb = sin_buf + (((size_t)bd * NHEADS_ + h) * 32 + c) * 4096;
        for (int un = tid; un < 512; un += 256) {
            const int ri = un >> 3, ch = un & 7;
            uint4 v = *reinterpret_cast<const uint4*>(sb + ri * 64 + ch * 8);
            *reinterpret_cast<uint4*>(&Ss[ri * PITCH + ch * 8]) = v;
        }
    }
    if (tid < 64) Pl[tid] = Pbuf[((size_t)bd * NHEADS_ + h) * L_SEQ + c * 64 + tid];
    __syncthreads();

    f32x4 accy[4];
#pragma unroll
    for (int nf = 0; nf < 4; ++nf) accy[nf] = (f32x4){0.f, 0.f, 0.f, 0.f};
#pragma unroll
    for (int s = 0; s < 2; ++s) {
        int koff = kg * 8 + s * 32;
        bf16x8 af = *reinterpret_cast<const bf16x8*>(&Cs[(i0 + fr) * PITCH + koff]);
#pragma unroll
        for (int nf = 0; nf < 4; ++nf) {
            bf16x8 bfv = *reinterpret_cast<const bf16x8*>(&Ss[(nf * 16 + fr) * PITCH + koff]);
            accy[nf] = __builtin_amdgcn_mfma_f32_16x16x32_bf16(af, bfv, accy[nf], 0, 0, 0);
        }
    }
    __syncthreads();

    ushort_t* Yt = (ushort_t*)Cs;
#pragma unroll
    for (int nf = 0; nf < 4; ++nf) {
        int hdl = nf * 16 + fr;
#pragma unroll
        for (int r = 0; r < 4; ++r) {
            int i = i0 + rg * 4 + r;
            Yt[i * 64 + hdl] = f2bf(accy[nf][r] * Pl[i]);
        }
    }
    __syncthreads();

    ushort_t* yout = dir ? ybw : yfw;
    for (int un = tid; un < 512; un += 256) {
        const int ri = un >> 3, ch = un & 7;
        int tau = c * 64 + ri;
        if (tau == L_SEQ - 1) continue;
        int tout = dir ? (L_SEQ - 2 - tau) : (tau + 1);
        ushort_t* gp = yout + ((size_t)beta * L_SEQ + tout) * DINNER + h * 64 + ch * 8;
        union U4 { uint4 v; ushort_t s[8]; } yo, cv, res;
        yo.v = *reinterpret_cast<const uint4*>(gp);
        cv.v = *reinterpret_cast<const uint4*>(Yt + ri * 64 + ch * 8);
#pragma unroll
        for (int k = 0; k < 8; ++k) res.s[k] = f2bf(bf2f(yo.s[k]) + bf2f(cv.s[k]));
        *reinterpret_cast<uint4*>(gp) = res.v;
    }
}

// ---------------- combine + RMSNorm + silu(z) gate -> bf16 y ---------------------------
__global__ __launch_bounds__(256)
void combine_rms(const ushort_t* __restrict__ yfw, const ushort_t* __restrict__ ybw,
                 const ushort_t* __restrict__ xBCbf, const float* __restrict__ dpart,
                 const float* __restrict__ Dp,
                 const ushort_t* __restrict__ zxbf, const float* __restrict__ norm_w,
                 ushort_t* __restrict__ ybf) {
    const int row = blockIdx.x;
    const int tid = threadIdx.x;
    union U4 { uint4 v; ushort_t s[8]; };
    U4 yf, yb, xv, zv;
    yf.v = *reinterpret_cast<const uint4*>(yfw + (size_t)row * DINNER + tid * 8);
    yb.v = *reinterpret_cast<const uint4*>(ybw + (size_t)row * DINNER + tid * 8);
    xv.v = *reinterpret_cast<const uint4*>(xBCbf + (size_t)row * CONVDIM + tid * 8);
    zv.v = *reinterpret_cast<const uint4*>(zxbf + (size_t)row * DINPROJ_P + tid * 8);
    const int hh = tid >> 3;
    float dgv = Dp[hh];
#pragma unroll
    for (int ks = 0; ks < KSPL; ++ks)
        dgv += dpart[((size_t)ks * (BATCH_ * L_SEQ) + row) * NHEADS_ + hh];
    float v[8];
    float ss = 0.f;
#pragma unroll
    for (int i = 0; i < 8; ++i) {
        float val = bf2f(yf.s[i]) + bf2f(yb.s[i]) + bf2f(xv.s[i]) * dgv;
        v[i] = val;
        ss += val * val;
    }
    ss += __shfl_xor(ss, 1);  ss += __shfl_xor(ss, 2);  ss += __shfl_xor(ss, 4);
    ss += __shfl_xor(ss, 8);  ss += __shfl_xor(ss, 16); ss += __shfl_xor(ss, 32);
    __shared__ float wsum[4];
    if ((tid & 63) == 0) wsum[tid >> 6] = ss;
    __syncthreads();
    ss = wsum[0] + wsum[1] + wsum[2] + wsum[3];
    const float inv = rsqrtf(ss * (1.f / DINNER) + EPS_);
    U4 outv;
#pragma unroll
    for (int i = 0; i < 8; ++i) {
        int c = tid * 8 + i;
        outv.s[i] = f2bf(norm_w[c] * v[i] * inv * silu_f(bf2f(zv.s[i])));
    }
    *reinterpret_cast<uint4*>(ybf + (size_t)row * DINNER + tid * 8) = outv.v;
}

extern "C" void kernel_launch(void* const* d_in, const int* in_sizes, int n_in,
                              void* d_out, int out_size, void* d_ws, size_t ws_size,
                              hipStream_t stream) {
    const float* u       = (const float*)d_in[0];
    const float* W_in    = (const float*)d_in[1];
    const float* conv_w  = (const float*)d_in[2];
    const float* conv_b  = (const float*)d_in[3];
    const float* dt_bias = (const float*)d_in[4];
    const float* A_log   = (const float*)d_in[5];
    const float* Dp      = (const float*)d_in[6];
    const float* fc_D_w  = (const float*)d_in[7];
    const float* norm_w  = (const float*)d_in[8];
    const float* W_out   = (const float*)d_in[9];
    float* out = (float*)d_out;

    const int ROWS = BATCH_ * L_SEQ;     // 4096
    // ---- workspace layout (~150 MB) ----
    ushort_t* zxbf  = (ushort_t*)d_ws;                            // 4096*4480 bf16
    ushort_t* xBCbf = zxbf  + (size_t)ROWS * DINPROJ_P;           // 4096*2304 bf16
    ushort_t* yfw   = xBCbf + (size_t)ROWS * CONVDIM;             // 4096*2048 bf16
    ushort_t* ybw   = yfw   + (size_t)ROWS * DINNER;              // 4096*2048 bf16
    float* dpart = (float*)(ybw + (size_t)ROWS * DINNER);         // 8*4096*32 f32
    float* labuf = dpart + (size_t)KSPL * ROWS * NHEADS_;         // 4*32*2048 f32
    float* Pbuf  = labuf + (size_t)4 * NHEADS_ * L_SEQ;           // 4*32*2048 f32
    ushort_t* sdel = (ushort_t*)(Pbuf + (size_t)4 * NHEADS_ * L_SEQ); // 4*32*32*64*64 bf16
    ushort_t* wobf = sdel + (size_t)4 * NHEADS_ * 32 * 64 * 64;   // 1024*2048 bf16
    ushort_t* fcdbf = wobf + (size_t)DMODEL * DINNER;             // 64*2048 bf16
    ushort_t* ubf  = fcdbf + (size_t)64 * DINNER;                 // 4096*1024 bf16
    ushort_t* wibf = ubf  + (size_t)ROWS * DMODEL;                // 4480*1024 bf16
    ushort_t* ybf  = ubf;   // reuse (ubf+wibf dead after gemm1)

    // 0. all dtype conversions in one launch
    const size_t total_units = N0U + N1U + N2U + N3U;
    cvt_all<<<(int)((total_units + 255) / 256), 256, 0, stream>>>(
        u, W_in, W_out, fc_D_w, ubf, wibf, wobf, fcdbf);

    // 1. in_proj GEMM (128-tile template, proven 70us): zxbf = u @ W_in^T
    gemm_nt_mfma<128, 128, 2, 2, 4, 4, 1><<<(ROWS / 128) * (DINPROJ_P / 128), 256, 0, stream>>>(
        ubf, wibf, nullptr, zxbf, ROWS, DINPROJ_P, DMODEL, DMODEL, DMODEL, DINPROJ_P / 128);

    // 2. depthwise conv + SiLU -> bf16 xBC
    dim3 gc(CONVDIM / 256, L_SEQ / 16, BATCH_);
    conv_kernel<<<gc, 256, 0, stream>>>(zxbf, conv_w, conv_b, xBCbf);

    // 2b. log-decay precompute
    dtla_kernel<<<(4 * L_SEQ * NHEADS_) / 256, 256, 0, stream>>>(zxbf, dt_bias, A_log, labuf);

    // 3a. SSD chunk-parallel intra work (Y_intra -> yfw/ybw, S_delta -> sdel bf16)
    dim3 ga(32, NHEADS_, 4);
    ssd_chunk_kernel<<<ga, 256, 0, stream>>>(xBCbf, labuf, Pbuf, sdel, yfw, ybw);

    // 3b. element-wise state scan (sdel overwritten in place with S_in prefixes)
    dim3 gsn(4 * NHEADS_, 4);
    ssd_scan_kernel<<<gsn, 256, 0, stream>>>(Pbuf, sdel);

    // 3c. chunk-parallel Y_inter RMW into yfw/ybw
    dim3 gy(32, NHEADS_, 4);
    ssd_yinter_kernel<<<gy, 256, 0, stream>>>(xBCbf, Pbuf, sdel, yfw, ybw);

    // 4. diag heads: K-split MFMA GEMM -> dpart[KSPL][4096][32]
    gemm_nt_mfma<64, 64, 2, 2, 2, 2, 2><<<(ROWS / 64) * KSPL, 256, 0, stream>>>(
        xBCbf, fcdbf, dpart, nullptr, ROWS, 64, DINNER, CONVDIM, DINNER, KSPL);

    // 5. combine + RMS norm + gate -> bf16 (sums diag partials + Dp)
    combine_rms<<<ROWS, 256, 0, stream>>>(yfw, ybw, xBCbf, dpart, Dp, zxbf, norm_w, ybf);

    // 6. out_proj GEMM (128-tile template): out = y @ W_out^T
    gemm_nt_mfma<128, 64, 2, 2, 4, 2, 0><<<(ROWS / 128) * (DMODEL / 64), 256, 0, stream>>>(
        ybf, wobf, out, nullptr, ROWS, DMODEL, DINNER, DINNER, DINNER, DMODEL / 64);
}